// Round 4
// baseline (400.506 us; speedup 1.0000x reference)
//
#include <hip/hip_runtime.h>
#include <math.h>

#define S_ 2048
#define E_ 2048
#define H_ 16
#define D_ 128

typedef _Float16 f16;
typedef _Float16 f16x8 __attribute__((ext_vector_type(8)));
typedef _Float16 f16x4 __attribute__((ext_vector_type(4)));
typedef float f32x4 __attribute__((ext_vector_type(4)));

// async global->LDS, 16B per lane. LDS dest must be wave-uniform base + lane*16.
// Used ONLY in the m97-pattern GEMMs (issue -> barrier -> consume, adjacent).
#define GLDS(g, l)                                                            \
    __builtin_amdgcn_global_load_lds(                                         \
        (const __attribute__((address_space(1))) void*)(g),                   \
        (__attribute__((address_space(3))) void*)(l), 16, 0, 0)

// ---------------------------------------------------------------- convert
__global__ __launch_bounds__(256) void cvt_f32_f16(const float* __restrict__ in,
                                                   f16* __restrict__ out, int n) {
    int i = (blockIdx.x * 256 + threadIdx.x) * 4;
    if (i + 3 < n) {
        float4 v = *(const float4*)(in + i);
        f16x4 o;
        o[0] = (f16)v.x; o[1] = (f16)v.y; o[2] = (f16)v.z; o[3] = (f16)v.w;
        *(f16x4*)(out + i) = o;
    }
}

// ---------------------------------------------------------------- QKV GEMM (m97 structure)
__global__ __launch_bounds__(256) void gemm_qkv(const f16* __restrict__ A,
                                                const f16* __restrict__ B,
                                                const float* __restrict__ bias,
                                                f16* __restrict__ Qm,
                                                f16* __restrict__ Km,
                                                f16* __restrict__ VTm) {
    __shared__ __align__(16) f16 As[128 * 32];   // unpadded: required by global_load_lds
    __shared__ __align__(16) f16 Bs[128 * 32];
    const int tid  = threadIdx.x;
    const int lane = tid & 63, wave = tid >> 6;
    const int lm = lane & 15, quad = lane >> 4;
    const int wm = wave >> 1, wn = wave & 1;
    const int tn0 = blockIdx.x * 128;
    const int tm0 = blockIdx.y * 128;

    const int srow = tid >> 2, scol = (tid & 3) * 8;
    const f16* Ag0 = A + (size_t)(tm0 + srow) * E_ + scol;
    const f16* Ag1 = Ag0 + (size_t)64 * E_;
    const f16* Bg0 = B + (size_t)(tn0 + srow) * E_ + scol;
    const f16* Bg1 = Bg0 + (size_t)64 * E_;
    f16* Al0 = &As[tid * 8];
    f16* Al1 = &As[(256 + tid) * 8];
    f16* Bl0 = &Bs[tid * 8];
    f16* Bl1 = &Bs[(256 + tid) * 8];

    const f32x4 vzero = {0.f, 0.f, 0.f, 0.f};
    f32x4 acc[4][4];
#pragma unroll
    for (int i = 0; i < 4; i++)
#pragma unroll
        for (int j = 0; j < 4; j++) acc[i][j] = vzero;

    for (int k0 = 0; k0 < E_; k0 += 32) {
        __syncthreads();
        GLDS(Ag0 + k0, Al0); GLDS(Ag1 + k0, Al1);
        GLDS(Bg0 + k0, Bl0); GLDS(Bg1 + k0, Bl1);
        __syncthreads();
        f16x8 af[4], bfr[4];
#pragma unroll
        for (int i = 0; i < 4; i++)
            af[i] = *(const f16x8*)&As[(wm * 64 + i * 16 + lm) * 32 + quad * 8];
#pragma unroll
        for (int j = 0; j < 4; j++)
            bfr[j] = *(const f16x8*)&Bs[(wn * 64 + j * 16 + lm) * 32 + quad * 8];
#pragma unroll
        for (int i = 0; i < 4; i++)
#pragma unroll
            for (int j = 0; j < 4; j++)
                acc[i][j] = __builtin_amdgcn_mfma_f32_16x16x32_f16(af[i], bfr[j],
                                                                   acc[i][j], 0, 0, 0);
    }

    const float qscale = 0.08838834764831845f;  // 1/sqrt(128), prefolded into Q
#pragma unroll
    for (int i = 0; i < 4; i++) {
#pragma unroll
        for (int j = 0; j < 4; j++) {
            const int n = tn0 + wn * 64 + j * 16 + lm;
            const int which = n >> 11;
            const int h = (n >> 7) & 15;
            const int d = n & 127;
            const float bv = bias[n];
#pragma unroll
            for (int r = 0; r < 4; r++) {
                const int m = tm0 + wm * 64 + i * 16 + quad * 4 + r;
                float fv = acc[i][j][r] + bv;
                if (which == 0)      Qm[((size_t)h * S_ + m) * D_ + d] = (f16)(fv * qscale);
                else if (which == 1) Km[((size_t)h * S_ + m) * D_ + d] = (f16)fv;
                else                 VTm[((size_t)h * D_ + d) * S_ + m] = (f16)fv;
            }
        }
    }
}

// ---------------------------------------------------------------- attention (partial)
// BARRIER-FREE: K and V fragments are read DIRECTLY from global into MFMA
// operand registers (K+V = 1MB/head, 2 heads/XCD -> L2-resident; all 4 waves
// read identical fragments -> L1 reuse). No K/V LDS tiles, no staging, no
// __syncthreads -- each wave free-runs its kv range (Common-mistake #7: don't
// LDS-stage L2-fitting data). Ps stays: same-wave LDS transpose round-trip,
// in-order, no barrier needed. Flash-decode split retained: 1280 uniform
// blocks (head, 64-row q-tile, <=8 kv-tile segment); LDS 8KB -> occupancy
// VGPR-bound; launch_bounds(256,4).
__global__ __launch_bounds__(256, 4) void attn_part(const f16* __restrict__ Qm,
                                                    const f16* __restrict__ Km,
                                                    const f16* __restrict__ VTm,
                                                    f16* __restrict__ Om,
                                                    f16* __restrict__ Opart,
                                                    float2* __restrict__ Mlp) {
    __shared__ __align__(16) f16 Ps[4][16 * 64];  // per-wave P, XOR-swizzled

    const int tid  = threadIdx.x;
    const int lane = tid & 63, wave = tid >> 6;
    const int lm = lane & 15, quad = lane >> 4;
    const int bx = blockIdx.x;
    const int h  = bx & 15;
    const int u  = 79 - (bx >> 4);   // canonical unit index, heavy-first dispatch

    int qt, seg;
    if (u < 8)       { qt = u;                  seg = 0; }
    else if (u < 24) { qt = 8  + ((u - 8) >> 1);  seg = (u - 8) & 1; }
    else if (u < 48) { qt = 16 + (u - 24) / 3;    seg = (u - 24) % 3; }
    else             { qt = 24 + ((u - 48) >> 2); seg = (u - 48) & 3; }
    const int t0 = seg * 8;
    const int t1 = (t0 + 8 < qt + 1) ? (t0 + 8) : (qt + 1);

    const f16* KmH  = Km  + (size_t)h * S_ * D_;
    const f16* VTmH = VTm + (size_t)h * D_ * S_;
    const f16* QmH  = Qm  + (size_t)h * S_ * D_;

    const f32x4 vzero = {0.f, 0.f, 0.f, 0.f};
    f32x4 o[8];
#pragma unroll
    for (int f = 0; f < 8; f++) o[f] = vzero;
    float mi = -INFINITY, li = 0.f;

    const int q0c = qt * 64 + wave * 16;           // this wave's 16-row chunk
    const int qrow = q0c + lm;
    f16x8 qf[4];
#pragma unroll
    for (int kc = 0; kc < 4; kc++)
        qf[kc] = *(const f16x8*)(QmH + (size_t)(q0c + lm) * D_ + kc * 32 + quad * 8);

    char* psb = (char*)&Ps[wave][0];
    const int swz = (lm & 7) << 4;

    // per-lane base pointers for direct K/V fragment loads
    const f16* kbase = KmH + (size_t)lm * 128 + quad * 8;      // + k0*128 + j*2048 + kc*32
    const f16* vbase = VTmH + (size_t)lm * 2048 + quad * 8;    // + f*32768 + k0 + kc*32

    for (int t = t0; t < t1; t++) {
        const int k0 = t * 64;

        // ---- S^T = K * Q^T : C[m=key][n=qrow]; K fragments straight from L1/L2
        const f16* kt = kbase + (size_t)k0 * 128;
        f32x4 sfr[4];
        __builtin_amdgcn_s_setprio(1);
#pragma unroll
        for (int j = 0; j < 4; j++) {
            f32x4 a = vzero;
#pragma unroll
            for (int kc = 0; kc < 4; kc++) {
                f16x8 kf = *(const f16x8*)(kt + j * 2048 + kc * 32);
                a = __builtin_amdgcn_mfma_f32_16x16x32_f16(kf, qf[kc], a, 0, 0, 0);
            }
            sfr[j] = a;
        }
        __builtin_amdgcn_s_setprio(0);

        // ---- online softmax (qrow = q0c+lm; 16 key-scores per lane)
        const bool masked = (t == qt);
        float sv[4][4];
        float vmax = -3e38f;
#pragma unroll
        for (int j = 0; j < 4; j++)
#pragma unroll
            for (int r = 0; r < 4; r++) {
                float x = sfr[j][r];
                if (masked) {
                    int key = k0 + j * 16 + quad * 4 + r;
                    if (key > qrow) x = -1e30f;
                }
                sv[j][r] = x;
                vmax = fmaxf(vmax, x);
            }
        vmax = fmaxf(vmax, __shfl_xor(vmax, 16));
        vmax = fmaxf(vmax, __shfl_xor(vmax, 32));
        const float mn = fmaxf(mi, vmax);
        const float alpha = __expf(mi - mn);
        mi = mn;
        float rsum = 0.f;
#pragma unroll
        for (int j = 0; j < 4; j++) {
            f16x4 pk;
#pragma unroll
            for (int r = 0; r < 4; r++) {
                float pv = __expf(sv[j][r] - mn);
                rsum += pv;
                pk[r] = (f16)pv;
            }
            *(f16x4*)(psb + lm * 128 + ((j * 32 + quad * 8) ^ swz)) = pk;
        }
        rsum += __shfl_xor(rsum, 16);
        rsum += __shfl_xor(rsum, 32);
        li = li * alpha + rsum;
#pragma unroll
        for (int f = 0; f < 8; f++) {
            o[f][0] *= alpha; o[f][1] *= alpha; o[f][2] *= alpha; o[f][3] *= alpha;
        }

        // ---- O^T += V^T * P^T  (P same-wave LDS round-trip; V from L1/L2)
        f16x8 pb[2];
#pragma unroll
        for (int kc = 0; kc < 2; kc++)
            pb[kc] = *(const f16x8*)(psb + lm * 128 + ((kc * 64 + quad * 16) ^ swz));
        const f16* vt = vbase + k0;
        __builtin_amdgcn_s_setprio(1);
#pragma unroll
        for (int f = 0; f < 8; f++) {
#pragma unroll
            for (int kc = 0; kc < 2; kc++) {
                f16x8 vf = *(const f16x8*)(vt + (size_t)f * 32768 + kc * 32);
                o[f] = __builtin_amdgcn_mfma_f32_16x16x32_f16(vf, pb[kc], o[f], 0, 0, 0);
            }
        }
        __builtin_amdgcn_s_setprio(0);
    }

    const float inv = 1.f / li;
    if (qt < 8) {
        // single segment: normalized output directly
#pragma unroll
        for (int f = 0; f < 8; f++) {
            f16x4 ov;
#pragma unroll
            for (int r = 0; r < 4; r++) ov[r] = (f16)(o[f][r] * inv);
            *(f16x4*)(Om + (size_t)(q0c + lm) * E_ + h * 128 + f * 16 + quad * 4) = ov;
        }
    } else {
        // partial: NORMALIZED O (f16, bounded ~|V|) + per-row (m, l)
        const int unit = h * 80 + u;
        f16* op = Opart + (size_t)unit * 8192 + (wave * 16 + lm) * 128;
#pragma unroll
        for (int f = 0; f < 8; f++) {
            f16x4 ov;
#pragma unroll
            for (int r = 0; r < 4; r++) ov[r] = (f16)(o[f][r] * inv);
            *(f16x4*)(op + f * 16 + quad * 4) = ov;
        }
        if (quad == 0) Mlp[unit * 64 + wave * 16 + lm] = make_float2(mi, li);
    }
}

// ---------------------------------------------------------------- attention merge
// Combines <=4 kv-segment partials per (head, q-row) for rows >= 512.
// Partials are normalized; weight for segment s is exp(m_s - m) * l_s.
__global__ __launch_bounds__(256) void attn_merge(const f16* __restrict__ Opart,
                                                  const float2* __restrict__ Mlp,
                                                  f16* __restrict__ Om) {
    const int idx = blockIdx.x * 256 + threadIdx.x;   // 786432 total
    const int d4  = idx & 31;
    const int h   = (idx >> 5) & 15;
    const int r5  = idx >> 9;            // 0..1535
    const int row = 512 + r5;
    const int qt  = row >> 6;            // 8..31
    const int rw  = row & 63;
    const int nseg = (qt >> 3) + 1;      // 2..4
    int ub;
    if (qt < 16)      ub = 8  + 2 * (qt - 8);
    else if (qt < 24) ub = 24 + 3 * (qt - 16);
    else              ub = 48 + 4 * (qt - 24);
    const int base_unit = h * 80 + ub;

    float m = -INFINITY;
    for (int s = 0; s < nseg; s++)
        m = fmaxf(m, Mlp[(base_unit + s) * 64 + rw].x);

    float L = 0.f;
    float a0 = 0.f, a1 = 0.f, a2 = 0.f, a3 = 0.f;
    for (int s = 0; s < nseg; s++) {
        float2 ml = Mlp[(base_unit + s) * 64 + rw];
        float wl = __expf(ml.x - m) * ml.y;
        L += wl;
        f16x4 ov = *(const f16x4*)(Opart + (size_t)(base_unit + s) * 8192 + rw * 128 + d4 * 4);
        a0 += wl * (float)ov[0];
        a1 += wl * (float)ov[1];
        a2 += wl * (float)ov[2];
        a3 += wl * (float)ov[3];
    }
    const float inv = 1.f / L;
    f16x4 res;
    res[0] = (f16)(a0 * inv); res[1] = (f16)(a1 * inv);
    res[2] = (f16)(a2 * inv); res[3] = (f16)(a3 * inv);
    *(f16x4*)(Om + (size_t)row * E_ + h * 128 + d4 * 4) = res;
}

// ---------------------------------------------------------------- out GEMM (m97 structure)
__global__ __launch_bounds__(256) void gemm_out(const f16* __restrict__ A,
                                                const f16* __restrict__ B,
                                                const float* __restrict__ bias,
                                                float* __restrict__ Cout) {
    __shared__ __align__(16) f16 As[128 * 32];
    __shared__ __align__(16) f16 Bs[128 * 32];
    const int tid  = threadIdx.x;
    const int lane = tid & 63, wave = tid >> 6;
    const int lm = lane & 15, quad = lane >> 4;
    const int wm = wave >> 1, wn = wave & 1;
    const int tn0 = blockIdx.x * 128;
    const int tm0 = blockIdx.y * 128;

    const int srow = tid >> 2, scol = (tid & 3) * 8;
    const f16* Ag0 = A + (size_t)(tm0 + srow) * E_ + scol;
    const f16* Ag1 = Ag0 + (size_t)64 * E_;
    const f16* Bg0 = B + (size_t)(tn0 + srow) * E_ + scol;
    const f16* Bg1 = Bg0 + (size_t)64 * E_;
    f16* Al0 = &As[tid * 8];
    f16* Al1 = &As[(256 + tid) * 8];
    f16* Bl0 = &Bs[tid * 8];
    f16* Bl1 = &Bs[(256 + tid) * 8];

    const f32x4 vzero = {0.f, 0.f, 0.f, 0.f};
    f32x4 acc[4][4];
#pragma unroll
    for (int i = 0; i < 4; i++)
#pragma unroll
        for (int j = 0; j < 4; j++) acc[i][j] = vzero;

    for (int k0 = 0; k0 < E_; k0 += 32) {
        __syncthreads();
        GLDS(Ag0 + k0, Al0); GLDS(Ag1 + k0, Al1);
        GLDS(Bg0 + k0, Bl0); GLDS(Bg1 + k0, Bl1);
        __syncthreads();
        f16x8 af[4], bfr[4];
#pragma unroll
        for (int i = 0; i < 4; i++)
            af[i] = *(const f16x8*)&As[(wm * 64 + i * 16 + lm) * 32 + quad * 8];
#pragma unroll
        for (int j = 0; j < 4; j++)
            bfr[j] = *(const f16x8*)&Bs[(wn * 64 + j * 16 + lm) * 32 + quad * 8];
#pragma unroll
        for (int i = 0; i < 4; i++)
#pragma unroll
            for (int j = 0; j < 4; j++)
                acc[i][j] = __builtin_amdgcn_mfma_f32_16x16x32_f16(af[i], bfr[j],
                                                                   acc[i][j], 0, 0, 0);
    }

#pragma unroll
    for (int i = 0; i < 4; i++) {
#pragma unroll
        for (int j = 0; j < 4; j++) {
            const int n = tn0 + wn * 64 + j * 16 + lm;
            const float bv = bias[n];
#pragma unroll
            for (int r = 0; r < 4; r++) {
                const int m = tm0 + wm * 64 + i * 16 + quad * 4 + r;
                Cout[(size_t)m * E_ + n] = acc[i][j][r] + bv;
            }
        }
    }
}

// ---------------------------------------------------------------- launch
extern "C" void kernel_launch(void* const* d_in, const int* in_sizes, int n_in,
                              void* d_out, int out_size, void* d_ws, size_t ws_size,
                              hipStream_t stream) {
    const float* x     = (const float*)d_in[0];
    const float* w_qkv = (const float*)d_in[1];
    const float* b_qkv = (const float*)d_in[2];
    const float* w_out = (const float*)d_in[3];
    const float* b_out = (const float*)d_in[4];
    float* out = (float*)d_out;

    char* ws = (char*)d_ws;
    f16* xb  = (f16*)ws; ws += (size_t)S_ * E_ * 2;
    f16* wqb = (f16*)ws; ws += (size_t)3 * E_ * E_ * 2;
    f16* wob = (f16*)ws; ws += (size_t)E_ * E_ * 2;
    f16* Qm  = (f16*)ws; ws += (size_t)H_ * S_ * D_ * 2;
    f16* Km  = (f16*)ws; ws += (size_t)H_ * S_ * D_ * 2;
    f16* VTm = (f16*)ws; ws += (size_t)H_ * D_ * S_ * 2;
    f16* Om  = (f16*)ws; ws += (size_t)S_ * E_ * 2;

    // attn partials reuse the xb+wqb region (32MB, dead after gemm_qkv):
    // Opart 1280 units x 64 rows x 128 d (f16) = 20MB; Mlp 1280 x 64 float2 = 640KB.
    f16*    Opart = (f16*)d_ws;
    float2* Mlp   = (float2*)((char*)d_ws + (20u << 20));

    cvt_f32_f16<<<4096, 256, 0, stream>>>(x, xb, S_ * E_);
    cvt_f32_f16<<<12288, 256, 0, stream>>>(w_qkv, wqb, 3 * E_ * E_);
    cvt_f32_f16<<<4096, 256, 0, stream>>>(w_out, wob, E_ * E_);
    gemm_qkv<<<dim3(48, 16), 256, 0, stream>>>(xb, wqb, b_qkv, Qm, Km, VTm);
    attn_part<<<1280, 256, 0, stream>>>(Qm, Km, VTm, Om, Opart, Mlp);
    attn_merge<<<3072, 256, 0, stream>>>(Opart, Mlp, Om);
    gemm_out<<<dim3(16, 16), 256, 0, stream>>>(Om, wob, b_out, out);
}

// Round 5
// 326.553 us; speedup vs baseline: 1.2265x; 1.2265x over previous
//
#include <hip/hip_runtime.h>
#include <math.h>

#define S_ 2048
#define E_ 2048
#define H_ 16
#define D_ 128

typedef _Float16 f16;
typedef _Float16 f16x8 __attribute__((ext_vector_type(8)));
typedef _Float16 f16x4 __attribute__((ext_vector_type(4)));
typedef float f32x4 __attribute__((ext_vector_type(4)));

// async global->LDS, 16B per lane. LDS dest must be wave-uniform base + lane*16.
// Used ONLY in the m97-pattern GEMMs (issue -> barrier -> consume, adjacent).
#define GLDS(g, l)                                                            \
    __builtin_amdgcn_global_load_lds(                                         \
        (const __attribute__((address_space(1))) void*)(g),                   \
        (__attribute__((address_space(3))) void*)(l), 16, 0, 0)

// ---------------------------------------------------------------- convert (fused: x, w_qkv, w_out)
__global__ __launch_bounds__(256) void cvt_all(const float* __restrict__ x,
                                               const float* __restrict__ wq,
                                               const float* __restrict__ wo,
                                               f16* __restrict__ xb,
                                               f16* __restrict__ wqb,
                                               f16* __restrict__ wob) {
    const int b = blockIdx.x;
    const float* in;
    f16* out;
    int lb;
    if (b < 4096)       { in = x;  out = xb;  lb = b; }
    else if (b < 16384) { in = wq; out = wqb; lb = b - 4096; }
    else                { in = wo; out = wob; lb = b - 16384; }
    const int i = (lb * 256 + threadIdx.x) * 4;   // all regions are exact multiples of 1024 floats
    float4 v = *(const float4*)(in + i);
    f16x4 o;
    o[0] = (f16)v.x; o[1] = (f16)v.y; o[2] = (f16)v.z; o[3] = (f16)v.w;
    *(f16x4*)(out + i) = o;
}

// ---------------------------------------------------------------- QKV GEMM (m97 structure)
__global__ __launch_bounds__(256) void gemm_qkv(const f16* __restrict__ A,
                                                const f16* __restrict__ B,
                                                const float* __restrict__ bias,
                                                f16* __restrict__ Qm,
                                                f16* __restrict__ Km,
                                                f16* __restrict__ VTm) {
    __shared__ __align__(16) f16 As[128 * 32];   // unpadded: required by global_load_lds
    __shared__ __align__(16) f16 Bs[128 * 32];
    const int tid  = threadIdx.x;
    const int lane = tid & 63, wave = tid >> 6;
    const int lm = lane & 15, quad = lane >> 4;
    const int wm = wave >> 1, wn = wave & 1;
    const int tn0 = blockIdx.x * 128;
    const int tm0 = blockIdx.y * 128;

    const int srow = tid >> 2, scol = (tid & 3) * 8;
    const f16* Ag0 = A + (size_t)(tm0 + srow) * E_ + scol;
    const f16* Ag1 = Ag0 + (size_t)64 * E_;
    const f16* Bg0 = B + (size_t)(tn0 + srow) * E_ + scol;
    const f16* Bg1 = Bg0 + (size_t)64 * E_;
    f16* Al0 = &As[tid * 8];
    f16* Al1 = &As[(256 + tid) * 8];
    f16* Bl0 = &Bs[tid * 8];
    f16* Bl1 = &Bs[(256 + tid) * 8];

    const f32x4 vzero = {0.f, 0.f, 0.f, 0.f};
    f32x4 acc[4][4];
#pragma unroll
    for (int i = 0; i < 4; i++)
#pragma unroll
        for (int j = 0; j < 4; j++) acc[i][j] = vzero;

    for (int k0 = 0; k0 < E_; k0 += 32) {
        __syncthreads();
        GLDS(Ag0 + k0, Al0); GLDS(Ag1 + k0, Al1);
        GLDS(Bg0 + k0, Bl0); GLDS(Bg1 + k0, Bl1);
        __syncthreads();
        f16x8 af[4], bfr[4];
#pragma unroll
        for (int i = 0; i < 4; i++)
            af[i] = *(const f16x8*)&As[(wm * 64 + i * 16 + lm) * 32 + quad * 8];
#pragma unroll
        for (int j = 0; j < 4; j++)
            bfr[j] = *(const f16x8*)&Bs[(wn * 64 + j * 16 + lm) * 32 + quad * 8];
#pragma unroll
        for (int i = 0; i < 4; i++)
#pragma unroll
            for (int j = 0; j < 4; j++)
                acc[i][j] = __builtin_amdgcn_mfma_f32_16x16x32_f16(af[i], bfr[j],
                                                                   acc[i][j], 0, 0, 0);
    }

    const float qscale = 0.08838834764831845f;  // 1/sqrt(128), prefolded into Q
#pragma unroll
    for (int i = 0; i < 4; i++) {
#pragma unroll
        for (int j = 0; j < 4; j++) {
            const int n = tn0 + wn * 64 + j * 16 + lm;
            const int which = n >> 11;
            const int h = (n >> 7) & 15;
            const int d = n & 127;
            const float bv = bias[n];
#pragma unroll
            for (int r = 0; r < 4; r++) {
                const int m = tm0 + wm * 64 + i * 16 + quad * 4 + r;
                float fv = acc[i][j][r] + bv;
                if (which == 0)      Qm[((size_t)h * S_ + m) * D_ + d] = (f16)(fv * qscale);
                else if (which == 1) Km[((size_t)h * S_ + m) * D_ + d] = (f16)fv;
                else                 VTm[((size_t)h * D_ + d) * S_ + m] = (f16)fv;
            }
        }
    }
}

// ---------------------------------------------------------------- attention
// R0-proven structure (reg-staged prefetch, 2 barriers/iter) with KVBLK=128:
// cross-round evidence (R0-R4) shows per-tile latency is quasi-fixed (~8k cy)
// and independent of occupancy/schedule, so the lever is SERIAL DEPTH: 128-key
// tiles halve the tile count (32 -> 16-17) at ~1.3x per-tile cost.
// LDS 80KB (Ks 32K + VTs 32K + Ps 16K) -> 2 blocks/CU. Stripe mapping pairs
// heavy+light q-tiles on one CU: every pair sums to exactly 17 kv-iters.
__global__ __launch_bounds__(256, 2) void attn(const f16* __restrict__ Qm,
                                               const f16* __restrict__ Km,
                                               const f16* __restrict__ VTm,
                                               f16* __restrict__ Om) {
    __shared__ __align__(16) f16 Ks[128 * 128];   // [key][d-chunk swizzled]
    __shared__ __align__(16) f16 VTs[128 * 128];  // [d][key-chunk swizzled]
    __shared__ __align__(16) f16 Ps[4][16 * 128]; // per-wave P [qrow][key], XOR-swizzled

    const int tid  = threadIdx.x;
    const int lane = tid & 63, wave = tid >> 6;
    const int lm = lane & 15, quad = lane >> 4;
    const int bx = blockIdx.x;
    const int st = bx >> 4;                       // stripe-paired heavy/light
    const int qt = (st < 16) ? (31 - st) : (st - 16);
    const int h  = bx & 15;
    const int nIter = qt / 2 + 1;                 // 128-key tiles

    const f16* KmH  = Km  + (size_t)h * S_ * D_;
    const f16* VTmH = VTm + (size_t)h * D_ * S_;
    const f16* QmH  = Qm  + (size_t)h * S_ * D_;

    // staging: 8 Ks chunks + 8 VTs chunks of 16B per thread.
    // global offsets linear (coalesced); LDS offsets XOR-swizzled.
    int kg[8], kl[8], vg[8], vl[8];
#pragma unroll
    for (int rr = 0; rr < 8; rr++) {
        int c = rr * 256 + tid;
        int key = c >> 4, dc = c & 15;
        kg[rr] = key * 128 + dc * 8;
        kl[rr] = key * 128 + ((dc & 8) | ((dc & 7) ^ (key & 7))) * 8;
        int d = c >> 4, sc = c & 15;
        vg[rr] = d * 2048 + sc * 8;
        vl[rr] = d * 128 + ((sc & 8) | ((sc & 7) ^ (d & 7))) * 8;
    }

    const f32x4 vzero = {0.f, 0.f, 0.f, 0.f};
    f32x4 o[8];
#pragma unroll
    for (int f = 0; f < 8; f++) o[f] = vzero;
    float mi = -INFINITY, li = 0.f;

    const int q0c = qt * 64 + wave * 16;           // this wave's 16-row chunk
    const int qrow = q0c + lm;
    f16x8 qf[4];
#pragma unroll
    for (int kc = 0; kc < 4; kc++)
        qf[kc] = *(const f16x8*)(QmH + (size_t)(q0c + lm) * D_ + kc * 32 + quad * 8);

    // prefetch tile 0 into registers
    float4 kreg[8], vreg[8];
#pragma unroll
    for (int rr = 0; rr < 8; rr++) {
        kreg[rr] = *(const float4*)(KmH + kg[rr]);
        vreg[rr] = *(const float4*)(VTmH + vg[rr]);
    }

    char* psb = (char*)&Ps[wave][0];
    const int swz = (lm & 15) << 4;

    for (int t = 0; t < nIter; t++) {
        const int k0 = t * 128;

        __syncthreads();   // all waves done READING LDS from previous iter
#pragma unroll
        for (int rr = 0; rr < 8; rr++) {
            *(float4*)&Ks[kl[rr]] = kreg[rr];
            *(float4*)&VTs[vl[rr]] = vreg[rr];
        }
        if (t + 1 < nIter) {   // prefetch next tile; latency hides behind compute
            const int nt = t + 1;
#pragma unroll
            for (int rr = 0; rr < 8; rr++) {
                kreg[rr] = *(const float4*)(KmH + (size_t)nt * 16384 + kg[rr]);
                vreg[rr] = *(const float4*)(VTmH + nt * 128 + vg[rr]);
            }
        }
        __syncthreads();   // ds_writes visible

        // ---- S^T = K * Q^T : C[m=key][n=qrow], 8 key-groups of 16
        f32x4 sfr[8];
#pragma unroll
        for (int j = 0; j < 8; j++) {
            f32x4 a = vzero;
#pragma unroll
            for (int kc = 0; kc < 4; kc++) {
                int dc = kc * 4 + quad;
                int sc = (dc & 8) | ((dc & 7) ^ (lm & 7));
                f16x8 kf = *(const f16x8*)&Ks[(j * 16 + lm) * 128 + sc * 8];
                a = __builtin_amdgcn_mfma_f32_16x16x32_f16(kf, qf[kc], a, 0, 0, 0);
            }
            sfr[j] = a;
        }

        // ---- online softmax (qrow = q0c+lm; 32 key-scores per lane, in-place)
        const bool masked = (t == nIter - 1);
        float vmax = -3e38f;
#pragma unroll
        for (int j = 0; j < 8; j++)
#pragma unroll
            for (int r = 0; r < 4; r++) {
                float x = sfr[j][r];
                if (masked) {
                    int key = k0 + j * 16 + quad * 4 + r;
                    if (key > qrow) x = -1e30f;
                }
                sfr[j][r] = x;
                vmax = fmaxf(vmax, x);
            }
        vmax = fmaxf(vmax, __shfl_xor(vmax, 16));
        vmax = fmaxf(vmax, __shfl_xor(vmax, 32));
        const float mn = fmaxf(mi, vmax);
        const float alpha = __expf(mi - mn);
        mi = mn;
        float rsum = 0.f;
#pragma unroll
        for (int j = 0; j < 8; j++) {
            f16x4 pk;
#pragma unroll
            for (int r = 0; r < 4; r++) {
                float pv = __expf(sfr[j][r] - mn);
                rsum += pv;
                pk[r] = (f16)pv;
            }
            *(f16x4*)(psb + lm * 256 + ((j * 32 + quad * 8) ^ swz)) = pk;
        }
        rsum += __shfl_xor(rsum, 16);
        rsum += __shfl_xor(rsum, 32);
        li = li * alpha + rsum;
#pragma unroll
        for (int f = 0; f < 8; f++) {
            o[f][0] *= alpha; o[f][1] *= alpha; o[f][2] *= alpha; o[f][3] *= alpha;
        }

        // ---- O^T += V^T * P^T  (P read back same-wave: in-order LDS, no barrier)
        f16x8 pb[4];
#pragma unroll
        for (int kc = 0; kc < 4; kc++)
            pb[kc] = *(const f16x8*)(psb + lm * 256 + ((kc * 64 + quad * 16) ^ swz));
#pragma unroll
        for (int f = 0; f < 8; f++) {
#pragma unroll
            for (int kc = 0; kc < 4; kc++) {
                int sc = kc * 4 + quad;
                int scz = (sc & 8) | ((sc & 7) ^ (lm & 7));
                f16x8 vf = *(const f16x8*)&VTs[(f * 16 + lm) * 128 + scz * 8];
                o[f] = __builtin_amdgcn_mfma_f32_16x16x32_f16(vf, pb[kc], o[f], 0, 0, 0);
            }
        }
    }

    const float inv = 1.f / li;
#pragma unroll
    for (int f = 0; f < 8; f++) {
        f16x4 ov;
#pragma unroll
        for (int r = 0; r < 4; r++) ov[r] = (f16)(o[f][r] * inv);
        *(f16x4*)(Om + (size_t)(q0c + lm) * E_ + h * 128 + f * 16 + quad * 4) = ov;
    }
}

// ---------------------------------------------------------------- out GEMM (m97 structure, BM=64)
// Grid 16x32 = 512 blocks -> 2 blocks/CU (the old 128x128 grid was exactly 256
// blocks = 1 block/CU: the m114 inter-block latency-hiding mechanism disabled).
__global__ __launch_bounds__(256) void gemm_out(const f16* __restrict__ A,
                                                const f16* __restrict__ B,
                                                const float* __restrict__ bias,
                                                float* __restrict__ Cout) {
    __shared__ __align__(16) f16 As[64 * 32];
    __shared__ __align__(16) f16 Bs[128 * 32];
    const int tid  = threadIdx.x;
    const int lane = tid & 63, wave = tid >> 6;
    const int lm = lane & 15, quad = lane >> 4;
    const int wm = wave >> 1, wn = wave & 1;
    const int tn0 = blockIdx.x * 128;
    const int tm0 = blockIdx.y * 64;

    const int srow = tid >> 2, scol = (tid & 3) * 8;
    const f16* Ag0 = A + (size_t)(tm0 + srow) * E_ + scol;   // 64 rows: 1 GLDS
    const f16* Bg0 = B + (size_t)(tn0 + srow) * E_ + scol;
    const f16* Bg1 = Bg0 + (size_t)64 * E_;
    f16* Al0 = &As[tid * 8];
    f16* Bl0 = &Bs[tid * 8];
    f16* Bl1 = &Bs[(256 + tid) * 8];

    const f32x4 vzero = {0.f, 0.f, 0.f, 0.f};
    f32x4 acc[2][4];
#pragma unroll
    for (int i = 0; i < 2; i++)
#pragma unroll
        for (int j = 0; j < 4; j++) acc[i][j] = vzero;

    for (int k0 = 0; k0 < E_; k0 += 32) {
        __syncthreads();
        GLDS(Ag0 + k0, Al0);
        GLDS(Bg0 + k0, Bl0); GLDS(Bg1 + k0, Bl1);
        __syncthreads();
        f16x8 af[2], bfr[4];
#pragma unroll
        for (int i = 0; i < 2; i++)
            af[i] = *(const f16x8*)&As[(wm * 32 + i * 16 + lm) * 32 + quad * 8];
#pragma unroll
        for (int j = 0; j < 4; j++)
            bfr[j] = *(const f16x8*)&Bs[(wn * 64 + j * 16 + lm) * 32 + quad * 8];
#pragma unroll
        for (int i = 0; i < 2; i++)
#pragma unroll
            for (int j = 0; j < 4; j++)
                acc[i][j] = __builtin_amdgcn_mfma_f32_16x16x32_f16(af[i], bfr[j],
                                                                   acc[i][j], 0, 0, 0);
    }

#pragma unroll
    for (int i = 0; i < 2; i++) {
#pragma unroll
        for (int j = 0; j < 4; j++) {
            const int n = tn0 + wn * 64 + j * 16 + lm;
            const float bv = bias[n];
#pragma unroll
            for (int r = 0; r < 4; r++) {
                const int m = tm0 + wm * 32 + i * 16 + quad * 4 + r;
                Cout[(size_t)m * E_ + n] = acc[i][j][r] + bv;
            }
        }
    }
}

// ---------------------------------------------------------------- launch
extern "C" void kernel_launch(void* const* d_in, const int* in_sizes, int n_in,
                              void* d_out, int out_size, void* d_ws, size_t ws_size,
                              hipStream_t stream) {
    const float* x     = (const float*)d_in[0];
    const float* w_qkv = (const float*)d_in[1];
    const float* b_qkv = (const float*)d_in[2];
    const float* w_out = (const float*)d_in[3];
    const float* b_out = (const float*)d_in[4];
    float* out = (float*)d_out;

    char* ws = (char*)d_ws;
    f16* xb  = (f16*)ws; ws += (size_t)S_ * E_ * 2;
    f16* wqb = (f16*)ws; ws += (size_t)3 * E_ * E_ * 2;
    f16* wob = (f16*)ws; ws += (size_t)E_ * E_ * 2;
    f16* Qm  = (f16*)ws; ws += (size_t)H_ * S_ * D_ * 2;
    f16* Km  = (f16*)ws; ws += (size_t)H_ * S_ * D_ * 2;
    f16* VTm = (f16*)ws; ws += (size_t)H_ * D_ * S_ * 2;
    f16* Om  = (f16*)ws; ws += (size_t)S_ * E_ * 2;

    cvt_all<<<20480, 256, 0, stream>>>(x, w_qkv, w_out, xb, wqb, wob);
    gemm_qkv<<<dim3(48, 16), 256, 0, stream>>>(xb, wqb, b_qkv, Qm, Km, VTm);
    attn<<<512, 256, 0, stream>>>(Qm, Km, VTm, Om);
    gemm_out<<<dim3(16, 32), 256, 0, stream>>>(Om, wob, b_out, out);
}

// Round 6
// 314.418 us; speedup vs baseline: 1.2738x; 1.0386x over previous
//
#include <hip/hip_runtime.h>
#include <math.h>

#define S_ 2048
#define E_ 2048
#define H_ 16
#define D_ 128

typedef _Float16 f16;
typedef _Float16 f16x8 __attribute__((ext_vector_type(8)));
typedef _Float16 f16x4 __attribute__((ext_vector_type(4)));
typedef float f32x4 __attribute__((ext_vector_type(4)));

// async global->LDS, 16B per lane. LDS dest must be wave-uniform base + lane*16.
// Used ONLY in the m97-pattern GEMMs (issue -> barrier -> consume, adjacent).
#define GLDS(g, l)                                                            \
    __builtin_amdgcn_global_load_lds(                                         \
        (const __attribute__((address_space(1))) void*)(g),                   \
        (__attribute__((address_space(3))) void*)(l), 16, 0, 0)

// ---------------------------------------------------------------- convert (fused: x, w_qkv, w_out)
__global__ __launch_bounds__(256) void cvt_all(const float* __restrict__ x,
                                               const float* __restrict__ wq,
                                               const float* __restrict__ wo,
                                               f16* __restrict__ xb,
                                               f16* __restrict__ wqb,
                                               f16* __restrict__ wob) {
    const int b = blockIdx.x;
    const float* in;
    f16* out;
    int lb;
    if (b < 4096)       { in = x;  out = xb;  lb = b; }
    else if (b < 16384) { in = wq; out = wqb; lb = b - 4096; }
    else                { in = wo; out = wob; lb = b - 16384; }
    const int i = (lb * 256 + threadIdx.x) * 4;   // all regions are exact multiples of 1024 floats
    float4 v = *(const float4*)(in + i);
    f16x4 o;
    o[0] = (f16)v.x; o[1] = (f16)v.y; o[2] = (f16)v.z; o[3] = (f16)v.w;
    *(f16x4*)(out + i) = o;
}

// ---------------------------------------------------------------- QKV GEMM (m97 structure)
__global__ __launch_bounds__(256) void gemm_qkv(const f16* __restrict__ A,
                                                const f16* __restrict__ B,
                                                const float* __restrict__ bias,
                                                f16* __restrict__ Qm,
                                                f16* __restrict__ Km,
                                                f16* __restrict__ VTm) {
    __shared__ __align__(16) f16 As[128 * 32];   // unpadded: required by global_load_lds
    __shared__ __align__(16) f16 Bs[128 * 32];
    const int tid  = threadIdx.x;
    const int lane = tid & 63, wave = tid >> 6;
    const int lm = lane & 15, quad = lane >> 4;
    const int wm = wave >> 1, wn = wave & 1;
    const int tn0 = blockIdx.x * 128;
    const int tm0 = blockIdx.y * 128;

    const int srow = tid >> 2, scol = (tid & 3) * 8;
    const f16* Ag0 = A + (size_t)(tm0 + srow) * E_ + scol;
    const f16* Ag1 = Ag0 + (size_t)64 * E_;
    const f16* Bg0 = B + (size_t)(tn0 + srow) * E_ + scol;
    const f16* Bg1 = Bg0 + (size_t)64 * E_;
    f16* Al0 = &As[tid * 8];
    f16* Al1 = &As[(256 + tid) * 8];
    f16* Bl0 = &Bs[tid * 8];
    f16* Bl1 = &Bs[(256 + tid) * 8];

    const f32x4 vzero = {0.f, 0.f, 0.f, 0.f};
    f32x4 acc[4][4];
#pragma unroll
    for (int i = 0; i < 4; i++)
#pragma unroll
        for (int j = 0; j < 4; j++) acc[i][j] = vzero;

    for (int k0 = 0; k0 < E_; k0 += 32) {
        __syncthreads();
        GLDS(Ag0 + k0, Al0); GLDS(Ag1 + k0, Al1);
        GLDS(Bg0 + k0, Bl0); GLDS(Bg1 + k0, Bl1);
        __syncthreads();
        f16x8 af[4], bfr[4];
#pragma unroll
        for (int i = 0; i < 4; i++)
            af[i] = *(const f16x8*)&As[(wm * 64 + i * 16 + lm) * 32 + quad * 8];
#pragma unroll
        for (int j = 0; j < 4; j++)
            bfr[j] = *(const f16x8*)&Bs[(wn * 64 + j * 16 + lm) * 32 + quad * 8];
#pragma unroll
        for (int i = 0; i < 4; i++)
#pragma unroll
            for (int j = 0; j < 4; j++)
                acc[i][j] = __builtin_amdgcn_mfma_f32_16x16x32_f16(af[i], bfr[j],
                                                                   acc[i][j], 0, 0, 0);
    }

    const float qscale = 0.08838834764831845f;  // 1/sqrt(128), prefolded into Q
#pragma unroll
    for (int i = 0; i < 4; i++) {
#pragma unroll
        for (int j = 0; j < 4; j++) {
            const int n = tn0 + wn * 64 + j * 16 + lm;
            const int which = n >> 11;
            const int h = (n >> 7) & 15;
            const int d = n & 127;
            const float bv = bias[n];
#pragma unroll
            for (int r = 0; r < 4; r++) {
                const int m = tm0 + wm * 64 + i * 16 + quad * 4 + r;
                float fv = acc[i][j][r] + bv;
                if (which == 0)      Qm[((size_t)h * S_ + m) * D_ + d] = (f16)(fv * qscale);
                else if (which == 1) Km[((size_t)h * S_ + m) * D_ + d] = (f16)fv;
                else                 VTm[((size_t)h * D_ + d) * S_ + m] = (f16)fv;
            }
        }
    }
}

// ---------------------------------------------------------------- attention (partial)
// R5 evidence: throughput-bound on per-iteration LDS work (occupancy x2 = same
// time; per-tile cost scales with tile work). The 4 waves redundantly read the
// full K/V tiles (4x duplication). FIX: each wave owns 32 q-rows (2 n-tiles):
// every K/V LDS fragment feeds 2 MFMAs -> per-qrow LDS reads, staging, barriers
// and block-iters all HALVED (4352 vs 8448). Block = 128 q-rows.
// Grid: R2-proven flash-decode segmentation -> 640 uniform blocks
// (16 heads x 40 units, <=8 kv-tiles each), normalized partials + merge.
// LDS 48KB (Ks 16K + VTs 16K + Ps 16K); VGPR ~200 -> 2 blocks/CU.
__global__ __launch_bounds__(256, 2) void attn_part(const f16* __restrict__ Qm,
                                                    const f16* __restrict__ Km,
                                                    const f16* __restrict__ VTm,
                                                    f16* __restrict__ Om,
                                                    f16* __restrict__ Opart,
                                                    float2* __restrict__ Mlp) {
    __shared__ __align__(16) f16 Ks[64 * 128];    // [key][d-chunk swizzled]
    __shared__ __align__(16) f16 VTs[128 * 64];   // [d][key-chunk swizzled]
    __shared__ __align__(16) f16 Ps[4][2048];     // per-wave, per-n 16x64 XOR-swizzled

    const int tid  = threadIdx.x;
    const int lane = tid & 63, wave = tid >> 6;
    const int lm = lane & 15, quad = lane >> 4;
    const int bx = blockIdx.x;
    const int h  = bx & 15;
    const int u  = 39 - (bx >> 4);   // canonical unit index, heavy-first dispatch

    // unit -> (128-row q-tile qt, kv-segment seg). tiles(qt) = 2qt+2.
    int qt, seg;
    if (u < 4)       { qt = u;                    seg = 0; }
    else if (u < 12) { qt = 4  + ((u - 4) >> 1);  seg = (u - 4) & 1; }
    else if (u < 24) { qt = 8  + (u - 12) / 3;    seg = (u - 12) % 3; }
    else             { qt = 12 + ((u - 24) >> 2); seg = (u - 24) & 3; }
    const int t0 = seg * 8;
    const int ntiles = 2 * qt + 2;
    const int t1 = (t0 + 8 < ntiles) ? (t0 + 8) : ntiles;

    const f16* KmH  = Km  + (size_t)h * S_ * D_;
    const f16* VTmH = VTm + (size_t)h * D_ * S_;
    const f16* QmH  = Qm  + (size_t)h * S_ * D_;

    // staging: 4 Ks chunks + 4 VTs chunks of 16B per thread (R0/R2-proven).
    int kg[4], kl[4], vg[4], vl[4];
#pragma unroll
    for (int rr = 0; rr < 4; rr++) {
        int c = rr * 256 + tid;
        int key = c >> 4, dc = c & 15;
        kg[rr] = key * 128 + dc * 8;
        kl[rr] = key * 128 + ((dc & 8) | ((dc & 7) ^ (key & 7))) * 8;
        int d = c >> 3, sc = c & 7;
        vg[rr] = d * 2048 + sc * 8;
        vl[rr] = d * 64 + (sc ^ (d & 7)) * 8;
    }

    const f32x4 vzero = {0.f, 0.f, 0.f, 0.f};
    f32x4 o0[8], o1[8];
#pragma unroll
    for (int f = 0; f < 8; f++) { o0[f] = vzero; o1[f] = vzero; }
    float mi0 = -INFINITY, li0 = 0.f;
    float mi1 = -INFINITY, li1 = 0.f;

    const int q0c = qt * 128 + wave * 32;          // wave's 32-row chunk
    const int qr0 = q0c + lm;                      // n=0 row
    const int qr1 = q0c + 16 + lm;                 // n=1 row
    f16x8 qf0[4], qf1[4];
#pragma unroll
    for (int kc = 0; kc < 4; kc++) {
        qf0[kc] = *(const f16x8*)(QmH + (size_t)qr0 * D_ + kc * 32 + quad * 8);
        qf1[kc] = *(const f16x8*)(QmH + (size_t)qr1 * D_ + kc * 32 + quad * 8);
    }

    // prefetch first tile of this segment into registers
    float4 kreg[4], vreg[4];
#pragma unroll
    for (int rr = 0; rr < 4; rr++) {
        kreg[rr] = *(const float4*)(KmH + (size_t)t0 * 8192 + kg[rr]);
        vreg[rr] = *(const float4*)(VTmH + t0 * 64 + vg[rr]);
    }

    char* psb = (char*)&Ps[wave][0];
    const int swz = (lm & 7) << 4;

    for (int t = t0; t < t1; t++) {
        const int k0 = t * 64;

        __syncthreads();   // all waves done READING LDS from previous iter
#pragma unroll
        for (int rr = 0; rr < 4; rr++) {
            *(float4*)&Ks[kl[rr]] = kreg[rr];
            *(float4*)&VTs[vl[rr]] = vreg[rr];
        }
        if (t + 1 < t1) {   // prefetch next tile; latency hides behind compute (TLP)
            const int nt = t + 1;
#pragma unroll
            for (int rr = 0; rr < 4; rr++) {
                kreg[rr] = *(const float4*)(KmH + (size_t)nt * 8192 + kg[rr]);
                vreg[rr] = *(const float4*)(VTmH + nt * 64 + vg[rr]);
            }
        }
        __syncthreads();   // ds_writes visible

        // ---- S^T = K * Q^T : each kf read feeds BOTH n-tiles
        f32x4 sfr0[4], sfr1[4];
        __builtin_amdgcn_s_setprio(1);
#pragma unroll
        for (int j = 0; j < 4; j++) {
            f32x4 a0 = vzero, a1 = vzero;
#pragma unroll
            for (int kc = 0; kc < 4; kc++) {
                int dc = kc * 4 + quad;
                int sc = (dc & 8) | ((dc & 7) ^ (lm & 7));
                f16x8 kf = *(const f16x8*)&Ks[(j * 16 + lm) * 128 + sc * 8];
                a0 = __builtin_amdgcn_mfma_f32_16x16x32_f16(kf, qf0[kc], a0, 0, 0, 0);
                a1 = __builtin_amdgcn_mfma_f32_16x16x32_f16(kf, qf1[kc], a1, 0, 0, 0);
            }
            sfr0[j] = a0; sfr1[j] = a1;
        }
        __builtin_amdgcn_s_setprio(0);

        // ---- online softmax, two independent 16-row chains (n=0, n=1)
        const bool mayMask = (k0 + 63 > q0c);
        float vmax0 = -3e38f, vmax1 = -3e38f;
#pragma unroll
        for (int j = 0; j < 4; j++)
#pragma unroll
            for (int r = 0; r < 4; r++) {
                float x0 = sfr0[j][r], x1 = sfr1[j][r];
                if (mayMask) {
                    int key = k0 + j * 16 + quad * 4 + r;
                    if (key > qr0) x0 = -1e30f;
                    if (key > qr1) x1 = -1e30f;
                }
                sfr0[j][r] = x0; sfr1[j][r] = x1;
                vmax0 = fmaxf(vmax0, x0);
                vmax1 = fmaxf(vmax1, x1);
            }
        vmax0 = fmaxf(vmax0, __shfl_xor(vmax0, 16));
        vmax0 = fmaxf(vmax0, __shfl_xor(vmax0, 32));
        vmax1 = fmaxf(vmax1, __shfl_xor(vmax1, 16));
        vmax1 = fmaxf(vmax1, __shfl_xor(vmax1, 32));
        const float mn0 = fmaxf(mi0, vmax0);
        const float mn1 = fmaxf(mi1, vmax1);
        const float al0 = __expf(mi0 - mn0);
        const float al1 = __expf(mi1 - mn1);
        mi0 = mn0; mi1 = mn1;
        float rs0 = 0.f, rs1 = 0.f;
#pragma unroll
        for (int j = 0; j < 4; j++) {
            f16x4 pk0, pk1;
#pragma unroll
            for (int r = 0; r < 4; r++) {
                float p0 = __expf(sfr0[j][r] - mn0);
                float p1 = __expf(sfr1[j][r] - mn1);
                rs0 += p0; rs1 += p1;
                pk0[r] = (f16)p0; pk1[r] = (f16)p1;
            }
            *(f16x4*)(psb + lm * 128 + ((j * 32 + quad * 8) ^ swz)) = pk0;
            *(f16x4*)(psb + 2048 + lm * 128 + ((j * 32 + quad * 8) ^ swz)) = pk1;
        }
        rs0 += __shfl_xor(rs0, 16);
        rs0 += __shfl_xor(rs0, 32);
        rs1 += __shfl_xor(rs1, 16);
        rs1 += __shfl_xor(rs1, 32);
        li0 = li0 * al0 + rs0;
        li1 = li1 * al1 + rs1;
#pragma unroll
        for (int f = 0; f < 8; f++) {
            o0[f][0] *= al0; o0[f][1] *= al0; o0[f][2] *= al0; o0[f][3] *= al0;
            o1[f][0] *= al1; o1[f][1] *= al1; o1[f][2] *= al1; o1[f][3] *= al1;
        }

        // ---- O^T += V^T * P^T : each vf read feeds BOTH n-tiles
        f16x8 pb0[2], pb1[2];
#pragma unroll
        for (int kc = 0; kc < 2; kc++) {
            pb0[kc] = *(const f16x8*)(psb + lm * 128 + ((kc * 64 + quad * 16) ^ swz));
            pb1[kc] = *(const f16x8*)(psb + 2048 + lm * 128 + ((kc * 64 + quad * 16) ^ swz));
        }
        __builtin_amdgcn_s_setprio(1);
#pragma unroll
        for (int f = 0; f < 8; f++) {
#pragma unroll
            for (int kc = 0; kc < 2; kc++) {
                int sc = (kc * 4 + quad) ^ (lm & 7);
                f16x8 vf = *(const f16x8*)&VTs[(f * 16 + lm) * 64 + sc * 8];
                o0[f] = __builtin_amdgcn_mfma_f32_16x16x32_f16(vf, pb0[kc], o0[f], 0, 0, 0);
                o1[f] = __builtin_amdgcn_mfma_f32_16x16x32_f16(vf, pb1[kc], o1[f], 0, 0, 0);
            }
        }
        __builtin_amdgcn_s_setprio(0);
    }

    const float inv0 = 1.f / li0;
    const float inv1 = 1.f / li1;
    if (qt < 4) {
        // single segment: normalized output directly
#pragma unroll
        for (int f = 0; f < 8; f++) {
            f16x4 ov0, ov1;
#pragma unroll
            for (int r = 0; r < 4; r++) {
                ov0[r] = (f16)(o0[f][r] * inv0);
                ov1[r] = (f16)(o1[f][r] * inv1);
            }
            *(f16x4*)(Om + (size_t)qr0 * E_ + h * 128 + f * 16 + quad * 4) = ov0;
            *(f16x4*)(Om + (size_t)qr1 * E_ + h * 128 + f * 16 + quad * 4) = ov1;
        }
    } else {
        // partial: NORMALIZED O (f16) + per-row (m, l)
        const int unit = h * 40 + u;
        f16* op0 = Opart + (size_t)unit * 16384 + (wave * 32 + lm) * 128;
        f16* op1 = op0 + 16 * 128;
#pragma unroll
        for (int f = 0; f < 8; f++) {
            f16x4 ov0, ov1;
#pragma unroll
            for (int r = 0; r < 4; r++) {
                ov0[r] = (f16)(o0[f][r] * inv0);
                ov1[r] = (f16)(o1[f][r] * inv1);
            }
            *(f16x4*)(op0 + f * 16 + quad * 4) = ov0;
            *(f16x4*)(op1 + f * 16 + quad * 4) = ov1;
        }
        if (quad == 0) {
            Mlp[unit * 128 + wave * 32 + lm]      = make_float2(mi0, li0);
            Mlp[unit * 128 + wave * 32 + 16 + lm] = make_float2(mi1, li1);
        }
    }
}

// ---------------------------------------------------------------- attention merge
// Combines <=4 kv-segment partials per (head, q-row) for rows >= 512.
// Partials are normalized; weight for segment s is exp(m_s - m) * l_s.
__global__ __launch_bounds__(256) void attn_merge(const f16* __restrict__ Opart,
                                                  const float2* __restrict__ Mlp,
                                                  f16* __restrict__ Om) {
    const int idx = blockIdx.x * 256 + threadIdx.x;   // 786432 total
    const int d4  = idx & 31;
    const int h   = (idx >> 5) & 15;
    const int r5  = idx >> 9;            // 0..1535
    const int row = 512 + r5;
    const int qt  = row >> 7;            // 4..15 (128-row tiles)
    const int rw  = row & 127;
    const int nseg = (qt >> 2) + 1;      // 2..4
    int ub;
    if (qt < 8)       ub = 4  + 2 * (qt - 4);
    else if (qt < 12) ub = 12 + 3 * (qt - 8);
    else              ub = 24 + 4 * (qt - 12);
    const int base_unit = h * 40 + ub;

    float m = -INFINITY;
    for (int s = 0; s < nseg; s++)
        m = fmaxf(m, Mlp[(base_unit + s) * 128 + rw].x);

    float L = 0.f;
    float a0 = 0.f, a1 = 0.f, a2 = 0.f, a3 = 0.f;
    for (int s = 0; s < nseg; s++) {
        float2 ml = Mlp[(base_unit + s) * 128 + rw];
        float wl = __expf(ml.x - m) * ml.y;
        L += wl;
        f16x4 ov = *(const f16x4*)(Opart + (size_t)(base_unit + s) * 16384 + rw * 128 + d4 * 4);
        a0 += wl * (float)ov[0];
        a1 += wl * (float)ov[1];
        a2 += wl * (float)ov[2];
        a3 += wl * (float)ov[3];
    }
    const float inv = 1.f / L;
    f16x4 res;
    res[0] = (f16)(a0 * inv); res[1] = (f16)(a1 * inv);
    res[2] = (f16)(a2 * inv); res[3] = (f16)(a3 * inv);
    *(f16x4*)(Om + (size_t)row * E_ + h * 128 + d4 * 4) = res;
}

// ---------------------------------------------------------------- out GEMM (m97 structure, BM=64)
__global__ __launch_bounds__(256) void gemm_out(const f16* __restrict__ A,
                                                const f16* __restrict__ B,
                                                const float* __restrict__ bias,
                                                float* __restrict__ Cout) {
    __shared__ __align__(16) f16 As[64 * 32];
    __shared__ __align__(16) f16 Bs[128 * 32];
    const int tid  = threadIdx.x;
    const int lane = tid & 63, wave = tid >> 6;
    const int lm = lane & 15, quad = lane >> 4;
    const int wm = wave >> 1, wn = wave & 1;
    const int tn0 = blockIdx.x * 128;
    const int tm0 = blockIdx.y * 64;

    const int srow = tid >> 2, scol = (tid & 3) * 8;
    const f16* Ag0 = A + (size_t)(tm0 + srow) * E_ + scol;   // 64 rows: 1 GLDS
    const f16* Bg0 = B + (size_t)(tn0 + srow) * E_ + scol;
    const f16* Bg1 = Bg0 + (size_t)64 * E_;
    f16* Al0 = &As[tid * 8];
    f16* Bl0 = &Bs[tid * 8];
    f16* Bl1 = &Bs[(256 + tid) * 8];

    const f32x4 vzero = {0.f, 0.f, 0.f, 0.f};
    f32x4 acc[2][4];
#pragma unroll
    for (int i = 0; i < 2; i++)
#pragma unroll
        for (int j = 0; j < 4; j++) acc[i][j] = vzero;

    for (int k0 = 0; k0 < E_; k0 += 32) {
        __syncthreads();
        GLDS(Ag0 + k0, Al0);
        GLDS(Bg0 + k0, Bl0); GLDS(Bg1 + k0, Bl1);
        __syncthreads();
        f16x8 af[2], bfr[4];
#pragma unroll
        for (int i = 0; i < 2; i++)
            af[i] = *(const f16x8*)&As[(wm * 32 + i * 16 + lm) * 32 + quad * 8];
#pragma unroll
        for (int j = 0; j < 4; j++)
            bfr[j] = *(const f16x8*)&Bs[(wn * 64 + j * 16 + lm) * 32 + quad * 8];
#pragma unroll
        for (int i = 0; i < 2; i++)
#pragma unroll
            for (int j = 0; j < 4; j++)
                acc[i][j] = __builtin_amdgcn_mfma_f32_16x16x32_f16(af[i], bfr[j],
                                                                   acc[i][j], 0, 0, 0);
    }

#pragma unroll
    for (int i = 0; i < 2; i++) {
#pragma unroll
        for (int j = 0; j < 4; j++) {
            const int n = tn0 + wn * 64 + j * 16 + lm;
            const float bv = bias[n];
#pragma unroll
            for (int r = 0; r < 4; r++) {
                const int m = tm0 + wm * 32 + i * 16 + quad * 4 + r;
                Cout[(size_t)m * E_ + n] = acc[i][j][r] + bv;
            }
        }
    }
}

// ---------------------------------------------------------------- launch
extern "C" void kernel_launch(void* const* d_in, const int* in_sizes, int n_in,
                              void* d_out, int out_size, void* d_ws, size_t ws_size,
                              hipStream_t stream) {
    const float* x     = (const float*)d_in[0];
    const float* w_qkv = (const float*)d_in[1];
    const float* b_qkv = (const float*)d_in[2];
    const float* w_out = (const float*)d_in[3];
    const float* b_out = (const float*)d_in[4];
    float* out = (float*)d_out;

    char* ws = (char*)d_ws;
    f16* xb  = (f16*)ws; ws += (size_t)S_ * E_ * 2;
    f16* wqb = (f16*)ws; ws += (size_t)3 * E_ * E_ * 2;
    f16* wob = (f16*)ws; ws += (size_t)E_ * E_ * 2;
    f16* Qm  = (f16*)ws; ws += (size_t)H_ * S_ * D_ * 2;
    f16* Km  = (f16*)ws; ws += (size_t)H_ * S_ * D_ * 2;
    f16* VTm = (f16*)ws; ws += (size_t)H_ * D_ * S_ * 2;
    f16* Om  = (f16*)ws; ws += (size_t)S_ * E_ * 2;

    // attn partials reuse the xb+wqb region (32MB, dead after gemm_qkv):
    // Opart 640 units x 128 rows x 128 d (f16) = 20MB; Mlp 640 x 128 float2 = 640KB.
    f16*    Opart = (f16*)d_ws;
    float2* Mlp   = (float2*)((char*)d_ws + (20u << 20));

    cvt_all<<<20480, 256, 0, stream>>>(x, w_qkv, w_out, xb, wqb, wob);
    gemm_qkv<<<dim3(48, 16), 256, 0, stream>>>(xb, wqb, b_qkv, Qm, Km, VTm);
    attn_part<<<640, 256, 0, stream>>>(Qm, Km, VTm, Om, Opart, Mlp);
    attn_merge<<<3072, 256, 0, stream>>>(Opart, Mlp, Om);
    gemm_out<<<dim3(16, 32), 256, 0, stream>>>(Om, wob, b_out, out);
}

// Round 7
// 268.035 us; speedup vs baseline: 1.4942x; 1.1730x over previous
//
#include <hip/hip_runtime.h>
#include <math.h>

#define S_ 2048
#define E_ 2048
#define H_ 16
#define D_ 128

typedef _Float16 f16;
typedef _Float16 f16x8 __attribute__((ext_vector_type(8)));
typedef _Float16 f16x4 __attribute__((ext_vector_type(4)));
typedef float f32x4 __attribute__((ext_vector_type(4)));

// async global->LDS, 16B per lane. LDS dest must be wave-uniform base + lane*16.
#define GLDS(g, l)                                                            \
    __builtin_amdgcn_global_load_lds(                                         \
        (const __attribute__((address_space(1))) void*)(g),                   \
        (__attribute__((address_space(3))) void*)(l), 16, 0, 0)

// ---------------------------------------------------------------- convert (fused: x, w_qkv, w_out)
__global__ __launch_bounds__(256) void cvt_all(const float* __restrict__ x,
                                               const float* __restrict__ wq,
                                               const float* __restrict__ wo,
                                               f16* __restrict__ xb,
                                               f16* __restrict__ wqb,
                                               f16* __restrict__ wob) {
    const int b = blockIdx.x;
    const float* in;
    f16* out;
    int lb;
    if (b < 4096)       { in = x;  out = xb;  lb = b; }
    else if (b < 16384) { in = wq; out = wqb; lb = b - 4096; }
    else                { in = wo; out = wob; lb = b - 16384; }
    const int i = (lb * 256 + threadIdx.x) * 4;
    float4 v = *(const float4*)(in + i);
    f16x4 o;
    o[0] = (f16)v.x; o[1] = (f16)v.y; o[2] = (f16)v.z; o[3] = (f16)v.w;
    *(f16x4*)(out + i) = o;
}

// ---------------------------------------------------------------- QKV GEMM (m97 structure)
__global__ __launch_bounds__(256) void gemm_qkv(const f16* __restrict__ A,
                                                const f16* __restrict__ B,
                                                const float* __restrict__ bias,
                                                f16* __restrict__ Qm,
                                                f16* __restrict__ Km,
                                                f16* __restrict__ VTm) {
    __shared__ __align__(16) f16 As[128 * 32];   // unpadded: required by global_load_lds
    __shared__ __align__(16) f16 Bs[128 * 32];
    const int tid  = threadIdx.x;
    const int lane = tid & 63, wave = tid >> 6;
    const int lm = lane & 15, quad = lane >> 4;
    const int wm = wave >> 1, wn = wave & 1;
    const int tn0 = blockIdx.x * 128;
    const int tm0 = blockIdx.y * 128;

    const int srow = tid >> 2, scol = (tid & 3) * 8;
    const f16* Ag0 = A + (size_t)(tm0 + srow) * E_ + scol;
    const f16* Ag1 = Ag0 + (size_t)64 * E_;
    const f16* Bg0 = B + (size_t)(tn0 + srow) * E_ + scol;
    const f16* Bg1 = Bg0 + (size_t)64 * E_;
    f16* Al0 = &As[tid * 8];
    f16* Al1 = &As[(256 + tid) * 8];
    f16* Bl0 = &Bs[tid * 8];
    f16* Bl1 = &Bs[(256 + tid) * 8];

    const f32x4 vzero = {0.f, 0.f, 0.f, 0.f};
    f32x4 acc[4][4];
#pragma unroll
    for (int i = 0; i < 4; i++)
#pragma unroll
        for (int j = 0; j < 4; j++) acc[i][j] = vzero;

    for (int k0 = 0; k0 < E_; k0 += 32) {
        __syncthreads();
        GLDS(Ag0 + k0, Al0); GLDS(Ag1 + k0, Al1);
        GLDS(Bg0 + k0, Bl0); GLDS(Bg1 + k0, Bl1);
        __syncthreads();
        f16x8 af[4], bfr[4];
#pragma unroll
        for (int i = 0; i < 4; i++)
            af[i] = *(const f16x8*)&As[(wm * 64 + i * 16 + lm) * 32 + quad * 8];
#pragma unroll
        for (int j = 0; j < 4; j++)
            bfr[j] = *(const f16x8*)&Bs[(wn * 64 + j * 16 + lm) * 32 + quad * 8];
#pragma unroll
        for (int i = 0; i < 4; i++)
#pragma unroll
            for (int j = 0; j < 4; j++)
                acc[i][j] = __builtin_amdgcn_mfma_f32_16x16x32_f16(af[i], bfr[j],
                                                                   acc[i][j], 0, 0, 0);
    }

    const float qscale = 0.08838834764831845f;  // 1/sqrt(128), prefolded into Q
#pragma unroll
    for (int i = 0; i < 4; i++) {
#pragma unroll
        for (int j = 0; j < 4; j++) {
            const int n = tn0 + wn * 64 + j * 16 + lm;
            const int which = n >> 11;
            const int h = (n >> 7) & 15;
            const int d = n & 127;
            const float bv = bias[n];
#pragma unroll
            for (int r = 0; r < 4; r++) {
                const int m = tm0 + wm * 64 + i * 16 + quad * 4 + r;
                float fv = acc[i][j][r] + bv;
                if (which == 0)      Qm[((size_t)h * S_ + m) * D_ + d] = (f16)(fv * qscale);
                else if (which == 1) Km[((size_t)h * S_ + m) * D_ + d] = (f16)fv;
                else                 VTm[((size_t)h * D_ + d) * S_ + m] = (f16)fv;
            }
        }
    }
}

// ---------------------------------------------------------------- attention (partial)
// LDS-pipe is the governing resource (R0-R6 evidence). This version removes
// per-iter staging traffic from the instruction stream:
//  - GLDS pre-swizzled staging (rule #21: linear LDS dest, inverse-XOR global
//    source, swizzled reads) -> no ds_writes, no reg staging, -32 VGPR.
//  - K/V double-buffered, ONE __syncthreads per iter (drains own-wave GLDS
//    after a full compute phase -> latency hidden).
//  - Ps shrunk to 2KB/wave (sequential P0/pb0/P1/pb1, same-wave in-order LDS).
//  - Defer-max (T13, THR=8): skip o-rescale chain on the common path.
// 2 q-row-tiles per wave (R6-proven sharing); 128-row blocks; flash-decode
// segments of 6 kv-tiles -> 816 uniform blocks; LDS 72KB -> 2 blocks/CU.
__global__ __launch_bounds__(256, 2) void attn_part(const f16* __restrict__ Qm,
                                                    const f16* __restrict__ Km,
                                                    const f16* __restrict__ VTm,
                                                    f16* __restrict__ Om,
                                                    f16* __restrict__ Opart,
                                                    float2* __restrict__ Mlp) {
    __shared__ __align__(16) f16 Ks[2][64 * 128];   // [buf][key][d-chunk swizzled]
    __shared__ __align__(16) f16 VTs[2][128 * 64];  // [buf][d][key-chunk swizzled]
    __shared__ __align__(16) f16 Ps[4][1024];       // per-wave 2KB, reused P0/P1

    const int tid  = threadIdx.x;
    const int lane = tid & 63, wave = tid >> 6;
    const int lm = lane & 15, quad = lane >> 4;
    const int bx = blockIdx.x;
    const int h  = bx & 15;
    const int u  = 50 - (bx >> 4);   // canonical unit index, heavy-first dispatch

    // unit -> (128-row q-tile qt, kv-segment of 6 tiles). tiles(qt) = 2qt+2.
    int qt, seg;
    if (u < 3)       { qt = u;                 seg = 0; }
    else if (u < 9)  { qt = 3  + (u - 3) / 2;  seg = (u - 3) % 2; }
    else if (u < 18) { qt = 6  + (u - 9) / 3;  seg = (u - 9) % 3; }
    else if (u < 30) { qt = 9  + (u - 18) / 4; seg = (u - 18) % 4; }
    else if (u < 45) { qt = 12 + (u - 30) / 5; seg = (u - 30) % 5; }
    else             { qt = 15;                seg = u - 45; }
    const int t0 = seg * 6;
    const int ntiles = 2 * qt + 2;
    const int t1 = (t0 + 6 < ntiles) ? (t0 + 6) : ntiles;

    const f16* KmH  = Km  + (size_t)h * S_ * D_;
    const f16* VTmH = VTm + (size_t)h * D_ * S_;
    const f16* QmH  = Qm  + (size_t)h * S_ * D_;

    // GLDS staging offsets: linear LDS slot c -> inverse-swizzled global chunk.
    // K: slot (key, dcS) holds global (key, dc), dc = (dcS&8)|((dcS&7)^(key&7)).
    // V: slot (d, scS)   holds global (d, sc),  sc = scS ^ (d&7).
    int kgo[4], vgo[4];
#pragma unroll
    for (int i = 0; i < 4; i++) {
        int c = (wave * 4 + i) * 64 + lane;          // 16B-chunk linear index
        int key = c >> 4, dcS = c & 15;
        int dc = (dcS & 8) | ((dcS & 7) ^ (key & 7));
        kgo[i] = key * 128 + dc * 8;
        int d = c >> 3, scS = c & 7;
        int sc = scS ^ (d & 7);
        vgo[i] = d * 2048 + sc * 8;
    }

#define STAGE(B, T)                                                           \
    {                                                                         \
        const f16* kt_ = KmH + (size_t)(T) * 8192;                            \
        const f16* vt_ = VTmH + (T) * 64;                                     \
        _Pragma("unroll")                                                     \
        for (int i = 0; i < 4; i++) {                                         \
            GLDS(kt_ + kgo[i], &Ks[B][(wave * 4 + i) * 512]);                 \
            GLDS(vt_ + vgo[i], &VTs[B][(wave * 4 + i) * 512]);                \
        }                                                                     \
    }

    const f32x4 vzero = {0.f, 0.f, 0.f, 0.f};
    f32x4 o0[8], o1[8];
#pragma unroll
    for (int f = 0; f < 8; f++) { o0[f] = vzero; o1[f] = vzero; }
    float mi0 = -INFINITY, li0 = 0.f;
    float mi1 = -INFINITY, li1 = 0.f;

    const int q0c = qt * 128 + wave * 32;          // wave's 32-row chunk
    const int qr0 = q0c + lm;                      // n=0 row
    const int qr1 = q0c + 16 + lm;                 // n=1 row
    f16x8 qf0[4], qf1[4];
#pragma unroll
    for (int kc = 0; kc < 4; kc++) {
        qf0[kc] = *(const f16x8*)(QmH + (size_t)qr0 * D_ + kc * 32 + quad * 8);
        qf1[kc] = *(const f16x8*)(QmH + (size_t)qr1 * D_ + kc * 32 + quad * 8);
    }

    char* psb = (char*)&Ps[wave][0];
    const int swz = (lm & 7) << 4;

    // prologue: stage first tile into buffer 0
    STAGE(0, t0);
    __syncthreads();

    for (int t = t0; t < t1; t++) {
        const int cur = (t - t0) & 1;
        const int k0 = t * 64;

        if (t + 1 < t1) STAGE(cur ^ 1, t + 1);   // async into other buffer

        // ---- S^T = K * Q^T : each kf read feeds BOTH n-tiles
        f32x4 sfr0[4], sfr1[4];
        __builtin_amdgcn_s_setprio(1);
#pragma unroll
        for (int j = 0; j < 4; j++) {
            f32x4 a0 = vzero, a1 = vzero;
#pragma unroll
            for (int kc = 0; kc < 4; kc++) {
                int dc = kc * 4 + quad;
                int sc = (dc & 8) | ((dc & 7) ^ (lm & 7));
                f16x8 kf = *(const f16x8*)&Ks[cur][(j * 16 + lm) * 128 + sc * 8];
                a0 = __builtin_amdgcn_mfma_f32_16x16x32_f16(kf, qf0[kc], a0, 0, 0, 0);
                a1 = __builtin_amdgcn_mfma_f32_16x16x32_f16(kf, qf1[kc], a1, 0, 0, 0);
            }
            sfr0[j] = a0; sfr1[j] = a1;
        }
        __builtin_amdgcn_s_setprio(0);

        // ---- online softmax, two independent 16-row chains (n=0, n=1)
        const bool mayMask = (k0 + 63 > q0c);
        float vmax0 = -3e38f, vmax1 = -3e38f;
#pragma unroll
        for (int j = 0; j < 4; j++)
#pragma unroll
            for (int r = 0; r < 4; r++) {
                float x0 = sfr0[j][r], x1 = sfr1[j][r];
                if (mayMask) {
                    int key = k0 + j * 16 + quad * 4 + r;
                    if (key > qr0) x0 = -1e30f;
                    if (key > qr1) x1 = -1e30f;
                }
                sfr0[j][r] = x0; sfr1[j][r] = x1;
                vmax0 = fmaxf(vmax0, x0);
                vmax1 = fmaxf(vmax1, x1);
            }
        vmax0 = fmaxf(vmax0, __shfl_xor(vmax0, 16));
        vmax0 = fmaxf(vmax0, __shfl_xor(vmax0, 32));
        vmax1 = fmaxf(vmax1, __shfl_xor(vmax1, 16));
        vmax1 = fmaxf(vmax1, __shfl_xor(vmax1, 32));
        // defer-max (T13): rescale only when a row's max grew by > 8
        if (!__all(fmaxf(vmax0 - mi0, vmax1 - mi1) <= 8.0f)) {
            const float mn0 = fmaxf(mi0, vmax0);
            const float mn1 = fmaxf(mi1, vmax1);
            const float al0 = __expf(mi0 - mn0);
            const float al1 = __expf(mi1 - mn1);
            li0 *= al0; li1 *= al1;
#pragma unroll
            for (int f = 0; f < 8; f++) {
                o0[f][0] *= al0; o0[f][1] *= al0; o0[f][2] *= al0; o0[f][3] *= al0;
                o1[f][0] *= al1; o1[f][1] *= al1; o1[f][2] *= al1; o1[f][3] *= al1;
            }
            mi0 = mn0; mi1 = mn1;
        }
        // P (bounded by e^8, f16-safe): n=0 through the 2KB Ps, then n=1
        float rs0 = 0.f, rs1 = 0.f;
#pragma unroll
        for (int j = 0; j < 4; j++) {
            f16x4 pk0;
#pragma unroll
            for (int r = 0; r < 4; r++) {
                float p0 = __expf(sfr0[j][r] - mi0);
                rs0 += p0;
                pk0[r] = (f16)p0;
            }
            *(f16x4*)(psb + lm * 128 + ((j * 32 + quad * 8) ^ swz)) = pk0;
        }
        f16x8 pb0[2];
#pragma unroll
        for (int kc = 0; kc < 2; kc++)
            pb0[kc] = *(const f16x8*)(psb + lm * 128 + ((kc * 64 + quad * 16) ^ swz));
#pragma unroll
        for (int j = 0; j < 4; j++) {
            f16x4 pk1;
#pragma unroll
            for (int r = 0; r < 4; r++) {
                float p1 = __expf(sfr1[j][r] - mi1);
                rs1 += p1;
                pk1[r] = (f16)p1;
            }
            *(f16x4*)(psb + lm * 128 + ((j * 32 + quad * 8) ^ swz)) = pk1;
        }
        f16x8 pb1[2];
#pragma unroll
        for (int kc = 0; kc < 2; kc++)
            pb1[kc] = *(const f16x8*)(psb + lm * 128 + ((kc * 64 + quad * 16) ^ swz));
        rs0 += __shfl_xor(rs0, 16);
        rs0 += __shfl_xor(rs0, 32);
        rs1 += __shfl_xor(rs1, 16);
        rs1 += __shfl_xor(rs1, 32);
        li0 += rs0;
        li1 += rs1;

        // ---- O^T += V^T * P^T : each vf read feeds BOTH n-tiles
        __builtin_amdgcn_s_setprio(1);
#pragma unroll
        for (int f = 0; f < 8; f++) {
#pragma unroll
            for (int kc = 0; kc < 2; kc++) {
                int sc = (kc * 4 + quad) ^ (lm & 7);
                f16x8 vf = *(const f16x8*)&VTs[cur][(f * 16 + lm) * 64 + sc * 8];
                o0[f] = __builtin_amdgcn_mfma_f32_16x16x32_f16(vf, pb0[kc], o0[f], 0, 0, 0);
                o1[f] = __builtin_amdgcn_mfma_f32_16x16x32_f16(vf, pb1[kc], o1[f], 0, 0, 0);
            }
        }
        __builtin_amdgcn_s_setprio(0);

        __syncthreads();   // own GLDS drained (hidden by compute); all waves done
    }

    const float inv0 = 1.f / li0;
    const float inv1 = 1.f / li1;
    if (qt < 3) {
        // single segment: normalized output directly
#pragma unroll
        for (int f = 0; f < 8; f++) {
            f16x4 ov0, ov1;
#pragma unroll
            for (int r = 0; r < 4; r++) {
                ov0[r] = (f16)(o0[f][r] * inv0);
                ov1[r] = (f16)(o1[f][r] * inv1);
            }
            *(f16x4*)(Om + (size_t)qr0 * E_ + h * 128 + f * 16 + quad * 4) = ov0;
            *(f16x4*)(Om + (size_t)qr1 * E_ + h * 128 + f * 16 + quad * 4) = ov1;
        }
    } else {
        // partial: NORMALIZED O (f16) + per-row (m, l)
        const int unit = h * 51 + u;
        f16* op0 = Opart + (size_t)unit * 16384 + (wave * 32 + lm) * 128;
        f16* op1 = op0 + 16 * 128;
#pragma unroll
        for (int f = 0; f < 8; f++) {
            f16x4 ov0, ov1;
#pragma unroll
            for (int r = 0; r < 4; r++) {
                ov0[r] = (f16)(o0[f][r] * inv0);
                ov1[r] = (f16)(o1[f][r] * inv1);
            }
            *(f16x4*)(op0 + f * 16 + quad * 4) = ov0;
            *(f16x4*)(op1 + f * 16 + quad * 4) = ov1;
        }
        if (quad == 0) {
            Mlp[unit * 128 + wave * 32 + lm]      = make_float2(mi0, li0);
            Mlp[unit * 128 + wave * 32 + 16 + lm] = make_float2(mi1, li1);
        }
    }
#undef STAGE
}

// ---------------------------------------------------------------- attention merge
// Combines <=6 kv-segment partials per (head, q-row) for rows >= 384.
// Partials are normalized; weight for segment s is exp(m_s - m) * l_s.
__global__ __launch_bounds__(256) void attn_merge(const f16* __restrict__ Opart,
                                                  const float2* __restrict__ Mlp,
                                                  f16* __restrict__ Om) {
    const int idx = blockIdx.x * 256 + threadIdx.x;   // 851968 total
    const int d4  = idx & 31;
    const int h   = (idx >> 5) & 15;
    const int r5  = idx >> 9;            // 0..1663
    const int row = 384 + r5;
    const int qt  = row >> 7;            // 3..15 (128-row tiles)
    const int rw  = row & 127;
    int ub, nseg;
    if (qt < 6)       { ub = 3  + (qt - 3) * 2;  nseg = 2; }
    else if (qt < 9)  { ub = 9  + (qt - 6) * 3;  nseg = 3; }
    else if (qt < 12) { ub = 18 + (qt - 9) * 4;  nseg = 4; }
    else if (qt < 15) { ub = 30 + (qt - 12) * 5; nseg = 5; }
    else              { ub = 45;                 nseg = 6; }
    const int base_unit = h * 51 + ub;

    float m = -INFINITY;
    for (int s = 0; s < nseg; s++)
        m = fmaxf(m, Mlp[(base_unit + s) * 128 + rw].x);

    float L = 0.f;
    float a0 = 0.f, a1 = 0.f, a2 = 0.f, a3 = 0.f;
    for (int s = 0; s < nseg; s++) {
        float2 ml = Mlp[(base_unit + s) * 128 + rw];
        float wl = __expf(ml.x - m) * ml.y;
        L += wl;
        f16x4 ov = *(const f16x4*)(Opart + (size_t)(base_unit + s) * 16384 + rw * 128 + d4 * 4);
        a0 += wl * (float)ov[0];
        a1 += wl * (float)ov[1];
        a2 += wl * (float)ov[2];
        a3 += wl * (float)ov[3];
    }
    const float inv = 1.f / L;
    f16x4 res;
    res[0] = (f16)(a0 * inv); res[1] = (f16)(a1 * inv);
    res[2] = (f16)(a2 * inv); res[3] = (f16)(a3 * inv);
    *(f16x4*)(Om + (size_t)row * E_ + h * 128 + d4 * 4) = res;
}

// ---------------------------------------------------------------- out GEMM (m97 structure, BM=64)
__global__ __launch_bounds__(256) void gemm_out(const f16* __restrict__ A,
                                                const f16* __restrict__ B,
                                                const float* __restrict__ bias,
                                                float* __restrict__ Cout) {
    __shared__ __align__(16) f16 As[64 * 32];
    __shared__ __align__(16) f16 Bs[128 * 32];
    const int tid  = threadIdx.x;
    const int lane = tid & 63, wave = tid >> 6;
    const int lm = lane & 15, quad = lane >> 4;
    const int wm = wave >> 1, wn = wave & 1;
    const int tn0 = blockIdx.x * 128;
    const int tm0 = blockIdx.y * 64;

    const int srow = tid >> 2, scol = (tid & 3) * 8;
    const f16* Ag0 = A + (size_t)(tm0 + srow) * E_ + scol;   // 64 rows: 1 GLDS
    const f16* Bg0 = B + (size_t)(tn0 + srow) * E_ + scol;
    const f16* Bg1 = Bg0 + (size_t)64 * E_;
    f16* Al0 = &As[tid * 8];
    f16* Bl0 = &Bs[tid * 8];
    f16* Bl1 = &Bs[(256 + tid) * 8];

    const f32x4 vzero = {0.f, 0.f, 0.f, 0.f};
    f32x4 acc[2][4];
#pragma unroll
    for (int i = 0; i < 2; i++)
#pragma unroll
        for (int j = 0; j < 4; j++) acc[i][j] = vzero;

    for (int k0 = 0; k0 < E_; k0 += 32) {
        __syncthreads();
        GLDS(Ag0 + k0, Al0);
        GLDS(Bg0 + k0, Bl0); GLDS(Bg1 + k0, Bl1);
        __syncthreads();
        f16x8 af[2], bfr[4];
#pragma unroll
        for (int i = 0; i < 2; i++)
            af[i] = *(const f16x8*)&As[(wm * 32 + i * 16 + lm) * 32 + quad * 8];
#pragma unroll
        for (int j = 0; j < 4; j++)
            bfr[j] = *(const f16x8*)&Bs[(wn * 64 + j * 16 + lm) * 32 + quad * 8];
#pragma unroll
        for (int i = 0; i < 2; i++)
#pragma unroll
            for (int j = 0; j < 4; j++)
                acc[i][j] = __builtin_amdgcn_mfma_f32_16x16x32_f16(af[i], bfr[j],
                                                                   acc[i][j], 0, 0, 0);
    }

#pragma unroll
    for (int i = 0; i < 2; i++) {
#pragma unroll
        for (int j = 0; j < 4; j++) {
            const int n = tn0 + wn * 64 + j * 16 + lm;
            const float bv = bias[n];
#pragma unroll
            for (int r = 0; r < 4; r++) {
                const int m = tm0 + wm * 32 + i * 16 + quad * 4 + r;
                Cout[(size_t)m * E_ + n] = acc[i][j][r] + bv;
            }
        }
    }
}

// ---------------------------------------------------------------- launch
extern "C" void kernel_launch(void* const* d_in, const int* in_sizes, int n_in,
                              void* d_out, int out_size, void* d_ws, size_t ws_size,
                              hipStream_t stream) {
    const float* x     = (const float*)d_in[0];
    const float* w_qkv = (const float*)d_in[1];
    const float* b_qkv = (const float*)d_in[2];
    const float* w_out = (const float*)d_in[3];
    const float* b_out = (const float*)d_in[4];
    float* out = (float*)d_out;

    char* ws = (char*)d_ws;
    f16* xb  = (f16*)ws; ws += (size_t)S_ * E_ * 2;
    f16* wqb = (f16*)ws; ws += (size_t)3 * E_ * E_ * 2;
    f16* wob = (f16*)ws; ws += (size_t)E_ * E_ * 2;
    f16* Qm  = (f16*)ws; ws += (size_t)H_ * S_ * D_ * 2;
    f16* Km  = (f16*)ws; ws += (size_t)H_ * S_ * D_ * 2;
    f16* VTm = (f16*)ws; ws += (size_t)H_ * D_ * S_ * 2;
    f16* Om  = (f16*)ws; ws += (size_t)S_ * E_ * 2;

    // attn partials reuse the xb+wqb region (32MB, dead after gemm_qkv):
    // Opart 816 units x 128 rows x 128 d (f16) = 25.5MB; Mlp 816 x 128 float2 at +27MB.
    f16*    Opart = (f16*)d_ws;
    float2* Mlp   = (float2*)((char*)d_ws + (27u << 20));

    cvt_all<<<20480, 256, 0, stream>>>(x, w_qkv, w_out, xb, wqb, wob);
    gemm_qkv<<<dim3(48, 16), 256, 0, stream>>>(xb, wqb, b_qkv, Qm, Km, VTm);
    attn_part<<<816, 256, 0, stream>>>(Qm, Km, VTm, Om, Opart, Mlp);
    attn_merge<<<3328, 256, 0, stream>>>(Opart, Mlp, Om);
    gemm_out<<<dim3(16, 32), 256, 0, stream>>>(Om, wob, b_out, out);
}

// Round 8
// 264.074 us; speedup vs baseline: 1.5166x; 1.0150x over previous
//
#include <hip/hip_runtime.h>
#include <math.h>

#define S_ 2048
#define E_ 2048
#define H_ 16
#define D_ 128

typedef _Float16 f16;
typedef _Float16 f16x8 __attribute__((ext_vector_type(8)));
typedef _Float16 f16x4 __attribute__((ext_vector_type(4)));
typedef float f32x4 __attribute__((ext_vector_type(4)));

// async global->LDS, 16B per lane. LDS dest must be wave-uniform base + lane*16.
#define GLDS(g, l)                                                            \
    __builtin_amdgcn_global_load_lds(                                         \
        (const __attribute__((address_space(1))) void*)(g),                   \
        (__attribute__((address_space(3))) void*)(l), 16, 0, 0)

// ---------------------------------------------------------------- convert (fused: x, w_qkv, w_out)
__global__ __launch_bounds__(256) void cvt_all(const float* __restrict__ x,
                                               const float* __restrict__ wq,
                                               const float* __restrict__ wo,
                                               f16* __restrict__ xb,
                                               f16* __restrict__ wqb,
                                               f16* __restrict__ wob) {
    const int b = blockIdx.x;
    const float* in;
    f16* out;
    int lb;
    if (b < 4096)       { in = x;  out = xb;  lb = b; }
    else if (b < 16384) { in = wq; out = wqb; lb = b - 4096; }
    else                { in = wo; out = wob; lb = b - 16384; }
    const int i = (lb * 256 + threadIdx.x) * 4;
    float4 v = *(const float4*)(in + i);
    f16x4 o;
    o[0] = (f16)v.x; o[1] = (f16)v.y; o[2] = (f16)v.z; o[3] = (f16)v.w;
    *(f16x4*)(out + i) = o;
}

// ---------------------------------------------------------------- QKV GEMM
// m97 structure upgraded: BK=64 (half the barriers), LDS XOR-swizzle via
// pre-swizzled GLDS source (rule #21: linear LDS dest, inverse-XOR global src,
// XOR on read) -> conflict-free b128 reads (was 8-way: row stride 64B=16 banks).
// T1 XCD-chunked block swizzle: 96 consecutive units per XCD = 2 A-panel rows
// -> A L2-resident per XCD. 768 blocks = 3/CU.
__global__ __launch_bounds__(256, 3) void gemm_qkv(const f16* __restrict__ A,
                                                   const f16* __restrict__ B,
                                                   const float* __restrict__ bias,
                                                   f16* __restrict__ Qm,
                                                   f16* __restrict__ Km,
                                                   f16* __restrict__ VTm) {
    __shared__ __align__(16) f16 As[128 * 64];   // [row][chunk-swizzled], 16KB
    __shared__ __align__(16) f16 Bs[128 * 64];
    const int tid  = threadIdx.x;
    const int lane = tid & 63, wave = tid >> 6;
    const int lm = lane & 15, quad = lane >> 4;
    const int wm = wave >> 1, wn = wave & 1;

    const int bid = blockIdx.x;                     // 1D grid, 768 blocks
    const int wid = (bid & 7) * 96 + (bid >> 3);    // bijective XCD chunking
    const int bx = wid % 48, by = wid / 48;
    const int tn0 = bx * 128, tm0 = by * 128;

    // staging: 4 chunks of 16B per thread per matrix; LDS linear, src inverse-swizzled
    const f16* Aga[4];
    const f16* Bga[4];
    f16* Ald[4];
    f16* Bld[4];
#pragma unroll
    for (int i = 0; i < 4; i++) {
        int c = i * 256 + tid;
        int row = c >> 3, ch = c & 7;
        int srcoff = row * E_ + ((ch ^ (row & 7)) * 8);
        Aga[i] = A + (size_t)tm0 * E_ + srcoff;
        Bga[i] = B + (size_t)tn0 * E_ + srcoff;
        Ald[i] = &As[c * 8];
        Bld[i] = &Bs[c * 8];
    }

    const f32x4 vzero = {0.f, 0.f, 0.f, 0.f};
    f32x4 acc[4][4];
#pragma unroll
    for (int i = 0; i < 4; i++)
#pragma unroll
        for (int j = 0; j < 4; j++) acc[i][j] = vzero;

    const int e7 = lm & 7;
    for (int k0 = 0; k0 < E_; k0 += 64) {
        __syncthreads();
#pragma unroll
        for (int i = 0; i < 4; i++) {
            GLDS(Aga[i] + k0, Ald[i]);
            GLDS(Bga[i] + k0, Bld[i]);
        }
        __syncthreads();
#pragma unroll
        for (int kk = 0; kk < 2; kk++) {
            f16x8 af[4], bfr[4];
#pragma unroll
            for (int i = 0; i < 4; i++)
                af[i] = *(const f16x8*)&As[(wm * 64 + i * 16 + lm) * 64 +
                                           (((kk * 4 + quad) ^ e7) * 8)];
#pragma unroll
            for (int j = 0; j < 4; j++)
                bfr[j] = *(const f16x8*)&Bs[(wn * 64 + j * 16 + lm) * 64 +
                                            (((kk * 4 + quad) ^ e7) * 8)];
#pragma unroll
            for (int i = 0; i < 4; i++)
#pragma unroll
                for (int j = 0; j < 4; j++)
                    acc[i][j] = __builtin_amdgcn_mfma_f32_16x16x32_f16(af[i], bfr[j],
                                                                       acc[i][j], 0, 0, 0);
        }
    }

    const float qscale = 0.08838834764831845f;  // 1/sqrt(128), prefolded into Q
#pragma unroll
    for (int i = 0; i < 4; i++) {
#pragma unroll
        for (int j = 0; j < 4; j++) {
            const int n = tn0 + wn * 64 + j * 16 + lm;
            const int which = n >> 11;
            const int h = (n >> 7) & 15;
            const int d = n & 127;
            const float bv = bias[n];
#pragma unroll
            for (int r = 0; r < 4; r++) {
                const int m = tm0 + wm * 64 + i * 16 + quad * 4 + r;
                float fv = acc[i][j][r] + bv;
                if (which == 0)      Qm[((size_t)h * S_ + m) * D_ + d] = (f16)(fv * qscale);
                else if (which == 1) Km[((size_t)h * S_ + m) * D_ + d] = (f16)fv;
                else                 VTm[((size_t)h * D_ + d) * S_ + m] = (f16)fv;
            }
        }
    }
}

// ---------------------------------------------------------------- attention (partial)
// R7 structure (verified): GLDS pre-swizzled staging, K/V double-buffered with
// ONE barrier/iter, Ps 2KB/wave, defer-max, 2 q-row-tiles/wave, flash-decode
// segments of 6 kv-tiles -> 816 uniform blocks; LDS 72KB -> 2 blocks/CU.
__global__ __launch_bounds__(256, 2) void attn_part(const f16* __restrict__ Qm,
                                                    const f16* __restrict__ Km,
                                                    const f16* __restrict__ VTm,
                                                    f16* __restrict__ Om,
                                                    f16* __restrict__ Opart,
                                                    float2* __restrict__ Mlp) {
    __shared__ __align__(16) f16 Ks[2][64 * 128];   // [buf][key][d-chunk swizzled]
    __shared__ __align__(16) f16 VTs[2][128 * 64];  // [buf][d][key-chunk swizzled]
    __shared__ __align__(16) f16 Ps[4][1024];       // per-wave 2KB, reused P0/P1

    const int tid  = threadIdx.x;
    const int lane = tid & 63, wave = tid >> 6;
    const int lm = lane & 15, quad = lane >> 4;
    const int bx = blockIdx.x;
    const int h  = bx & 15;
    const int u  = 50 - (bx >> 4);   // canonical unit index, heavy-first dispatch

    // unit -> (128-row q-tile qt, kv-segment of 6 tiles). tiles(qt) = 2qt+2.
    int qt, seg;
    if (u < 3)       { qt = u;                 seg = 0; }
    else if (u < 9)  { qt = 3  + (u - 3) / 2;  seg = (u - 3) % 2; }
    else if (u < 18) { qt = 6  + (u - 9) / 3;  seg = (u - 9) % 3; }
    else if (u < 30) { qt = 9  + (u - 18) / 4; seg = (u - 18) % 4; }
    else if (u < 45) { qt = 12 + (u - 30) / 5; seg = (u - 30) % 5; }
    else             { qt = 15;                seg = u - 45; }
    const int t0 = seg * 6;
    const int ntiles = 2 * qt + 2;
    const int t1 = (t0 + 6 < ntiles) ? (t0 + 6) : ntiles;

    const f16* KmH  = Km  + (size_t)h * S_ * D_;
    const f16* VTmH = VTm + (size_t)h * D_ * S_;
    const f16* QmH  = Qm  + (size_t)h * S_ * D_;

    // GLDS staging offsets: linear LDS slot c -> inverse-swizzled global chunk.
    int kgo[4], vgo[4];
#pragma unroll
    for (int i = 0; i < 4; i++) {
        int c = (wave * 4 + i) * 64 + lane;          // 16B-chunk linear index
        int key = c >> 4, dcS = c & 15;
        int dc = (dcS & 8) | ((dcS & 7) ^ (key & 7));
        kgo[i] = key * 128 + dc * 8;
        int d = c >> 3, scS = c & 7;
        int sc = scS ^ (d & 7);
        vgo[i] = d * 2048 + sc * 8;
    }

#define STAGE(B, T)                                                           \
    {                                                                         \
        const f16* kt_ = KmH + (size_t)(T) * 8192;                            \
        const f16* vt_ = VTmH + (T) * 64;                                     \
        _Pragma("unroll")                                                     \
        for (int i = 0; i < 4; i++) {                                         \
            GLDS(kt_ + kgo[i], &Ks[B][(wave * 4 + i) * 512]);                 \
            GLDS(vt_ + vgo[i], &VTs[B][(wave * 4 + i) * 512]);                \
        }                                                                     \
    }

    const f32x4 vzero = {0.f, 0.f, 0.f, 0.f};
    f32x4 o0[8], o1[8];
#pragma unroll
    for (int f = 0; f < 8; f++) { o0[f] = vzero; o1[f] = vzero; }
    float mi0 = -INFINITY, li0 = 0.f;
    float mi1 = -INFINITY, li1 = 0.f;

    const int q0c = qt * 128 + wave * 32;          // wave's 32-row chunk
    const int qr0 = q0c + lm;                      // n=0 row
    const int qr1 = q0c + 16 + lm;                 // n=1 row
    f16x8 qf0[4], qf1[4];
#pragma unroll
    for (int kc = 0; kc < 4; kc++) {
        qf0[kc] = *(const f16x8*)(QmH + (size_t)qr0 * D_ + kc * 32 + quad * 8);
        qf1[kc] = *(const f16x8*)(QmH + (size_t)qr1 * D_ + kc * 32 + quad * 8);
    }

    char* psb = (char*)&Ps[wave][0];
    const int swz = (lm & 7) << 4;

    // prologue: stage first tile into buffer 0
    STAGE(0, t0);
    __syncthreads();

    for (int t = t0; t < t1; t++) {
        const int cur = (t - t0) & 1;
        const int k0 = t * 64;

        if (t + 1 < t1) STAGE(cur ^ 1, t + 1);   // async into other buffer

        // ---- S^T = K * Q^T : each kf read feeds BOTH n-tiles
        f32x4 sfr0[4], sfr1[4];
        __builtin_amdgcn_s_setprio(1);
#pragma unroll
        for (int j = 0; j < 4; j++) {
            f32x4 a0 = vzero, a1 = vzero;
#pragma unroll
            for (int kc = 0; kc < 4; kc++) {
                int dc = kc * 4 + quad;
                int sc = (dc & 8) | ((dc & 7) ^ (lm & 7));
                f16x8 kf = *(const f16x8*)&Ks[cur][(j * 16 + lm) * 128 + sc * 8];
                a0 = __builtin_amdgcn_mfma_f32_16x16x32_f16(kf, qf0[kc], a0, 0, 0, 0);
                a1 = __builtin_amdgcn_mfma_f32_16x16x32_f16(kf, qf1[kc], a1, 0, 0, 0);
            }
            sfr0[j] = a0; sfr1[j] = a1;
        }
        __builtin_amdgcn_s_setprio(0);

        // ---- online softmax, two independent 16-row chains (n=0, n=1)
        const bool mayMask = (k0 + 63 > q0c);
        float vmax0 = -3e38f, vmax1 = -3e38f;
#pragma unroll
        for (int j = 0; j < 4; j++)
#pragma unroll
            for (int r = 0; r < 4; r++) {
                float x0 = sfr0[j][r], x1 = sfr1[j][r];
                if (mayMask) {
                    int key = k0 + j * 16 + quad * 4 + r;
                    if (key > qr0) x0 = -1e30f;
                    if (key > qr1) x1 = -1e30f;
                }
                sfr0[j][r] = x0; sfr1[j][r] = x1;
                vmax0 = fmaxf(vmax0, x0);
                vmax1 = fmaxf(vmax1, x1);
            }
        vmax0 = fmaxf(vmax0, __shfl_xor(vmax0, 16));
        vmax0 = fmaxf(vmax0, __shfl_xor(vmax0, 32));
        vmax1 = fmaxf(vmax1, __shfl_xor(vmax1, 16));
        vmax1 = fmaxf(vmax1, __shfl_xor(vmax1, 32));
        // defer-max (T13): rescale only when a row's max grew by > 8
        if (!__all(fmaxf(vmax0 - mi0, vmax1 - mi1) <= 8.0f)) {
            const float mn0 = fmaxf(mi0, vmax0);
            const float mn1 = fmaxf(mi1, vmax1);
            const float al0 = __expf(mi0 - mn0);
            const float al1 = __expf(mi1 - mn1);
            li0 *= al0; li1 *= al1;
#pragma unroll
            for (int f = 0; f < 8; f++) {
                o0[f][0] *= al0; o0[f][1] *= al0; o0[f][2] *= al0; o0[f][3] *= al0;
                o1[f][0] *= al1; o1[f][1] *= al1; o1[f][2] *= al1; o1[f][3] *= al1;
            }
            mi0 = mn0; mi1 = mn1;
        }
        // P (bounded by e^8, f16-safe): n=0 through the 2KB Ps, then n=1
        float rs0 = 0.f, rs1 = 0.f;
#pragma unroll
        for (int j = 0; j < 4; j++) {
            f16x4 pk0;
#pragma unroll
            for (int r = 0; r < 4; r++) {
                float p0 = __expf(sfr0[j][r] - mi0);
                rs0 += p0;
                pk0[r] = (f16)p0;
            }
            *(f16x4*)(psb + lm * 128 + ((j * 32 + quad * 8) ^ swz)) = pk0;
        }
        f16x8 pb0[2];
#pragma unroll
        for (int kc = 0; kc < 2; kc++)
            pb0[kc] = *(const f16x8*)(psb + lm * 128 + ((kc * 64 + quad * 16) ^ swz));
#pragma unroll
        for (int j = 0; j < 4; j++) {
            f16x4 pk1;
#pragma unroll
            for (int r = 0; r < 4; r++) {
                float p1 = __expf(sfr1[j][r] - mi1);
                rs1 += p1;
                pk1[r] = (f16)p1;
            }
            *(f16x4*)(psb + lm * 128 + ((j * 32 + quad * 8) ^ swz)) = pk1;
        }
        f16x8 pb1[2];
#pragma unroll
        for (int kc = 0; kc < 2; kc++)
            pb1[kc] = *(const f16x8*)(psb + lm * 128 + ((kc * 64 + quad * 16) ^ swz));
        rs0 += __shfl_xor(rs0, 16);
        rs0 += __shfl_xor(rs0, 32);
        rs1 += __shfl_xor(rs1, 16);
        rs1 += __shfl_xor(rs1, 32);
        li0 += rs0;
        li1 += rs1;

        // ---- O^T += V^T * P^T : each vf read feeds BOTH n-tiles
        __builtin_amdgcn_s_setprio(1);
#pragma unroll
        for (int f = 0; f < 8; f++) {
#pragma unroll
            for (int kc = 0; kc < 2; kc++) {
                int sc = (kc * 4 + quad) ^ (lm & 7);
                f16x8 vf = *(const f16x8*)&VTs[cur][(f * 16 + lm) * 64 + sc * 8];
                o0[f] = __builtin_amdgcn_mfma_f32_16x16x32_f16(vf, pb0[kc], o0[f], 0, 0, 0);
                o1[f] = __builtin_amdgcn_mfma_f32_16x16x32_f16(vf, pb1[kc], o1[f], 0, 0, 0);
            }
        }
        __builtin_amdgcn_s_setprio(0);

        __syncthreads();   // own GLDS drained (hidden by compute); all waves done
    }

    const float inv0 = 1.f / li0;
    const float inv1 = 1.f / li1;
    if (qt < 3) {
        // single segment: normalized output directly
#pragma unroll
        for (int f = 0; f < 8; f++) {
            f16x4 ov0, ov1;
#pragma unroll
            for (int r = 0; r < 4; r++) {
                ov0[r] = (f16)(o0[f][r] * inv0);
                ov1[r] = (f16)(o1[f][r] * inv1);
            }
            *(f16x4*)(Om + (size_t)qr0 * E_ + h * 128 + f * 16 + quad * 4) = ov0;
            *(f16x4*)(Om + (size_t)qr1 * E_ + h * 128 + f * 16 + quad * 4) = ov1;
        }
    } else {
        // partial: NORMALIZED O (f16) + per-row (m, l)
        const int unit = h * 51 + u;
        f16* op0 = Opart + (size_t)unit * 16384 + (wave * 32 + lm) * 128;
        f16* op1 = op0 + 16 * 128;
#pragma unroll
        for (int f = 0; f < 8; f++) {
            f16x4 ov0, ov1;
#pragma unroll
            for (int r = 0; r < 4; r++) {
                ov0[r] = (f16)(o0[f][r] * inv0);
                ov1[r] = (f16)(o1[f][r] * inv1);
            }
            *(f16x4*)(op0 + f * 16 + quad * 4) = ov0;
            *(f16x4*)(op1 + f * 16 + quad * 4) = ov1;
        }
        if (quad == 0) {
            Mlp[unit * 128 + wave * 32 + lm]      = make_float2(mi0, li0);
            Mlp[unit * 128 + wave * 32 + 16 + lm] = make_float2(mi1, li1);
        }
    }
#undef STAGE
}

// ---------------------------------------------------------------- attention merge
__global__ __launch_bounds__(256) void attn_merge(const f16* __restrict__ Opart,
                                                  const float2* __restrict__ Mlp,
                                                  f16* __restrict__ Om) {
    const int idx = blockIdx.x * 256 + threadIdx.x;   // 851968 total
    const int d4  = idx & 31;
    const int h   = (idx >> 5) & 15;
    const int r5  = idx >> 9;            // 0..1663
    const int row = 384 + r5;
    const int qt  = row >> 7;            // 3..15 (128-row tiles)
    const int rw  = row & 127;
    int ub, nseg;
    if (qt < 6)       { ub = 3  + (qt - 3) * 2;  nseg = 2; }
    else if (qt < 9)  { ub = 9  + (qt - 6) * 3;  nseg = 3; }
    else if (qt < 12) { ub = 18 + (qt - 9) * 4;  nseg = 4; }
    else if (qt < 15) { ub = 30 + (qt - 12) * 5; nseg = 5; }
    else              { ub = 45;                 nseg = 6; }
    const int base_unit = h * 51 + ub;

    float m = -INFINITY;
    for (int s = 0; s < nseg; s++)
        m = fmaxf(m, Mlp[(base_unit + s) * 128 + rw].x);

    float L = 0.f;
    float a0 = 0.f, a1 = 0.f, a2 = 0.f, a3 = 0.f;
    for (int s = 0; s < nseg; s++) {
        float2 ml = Mlp[(base_unit + s) * 128 + rw];
        float wl = __expf(ml.x - m) * ml.y;
        L += wl;
        f16x4 ov = *(const f16x4*)(Opart + (size_t)(base_unit + s) * 16384 + rw * 128 + d4 * 4);
        a0 += wl * (float)ov[0];
        a1 += wl * (float)ov[1];
        a2 += wl * (float)ov[2];
        a3 += wl * (float)ov[3];
    }
    const float inv = 1.f / L;
    f16x4 res;
    res[0] = (f16)(a0 * inv); res[1] = (f16)(a1 * inv);
    res[2] = (f16)(a2 * inv); res[3] = (f16)(a3 * inv);
    *(f16x4*)(Om + (size_t)row * E_ + h * 128 + d4 * 4) = res;
}

// ---------------------------------------------------------------- out GEMM
// Same upgrades: BK=64, swizzled LDS via pre-swizzled GLDS source, T1 grid
// swizzle. BM=64 x BN=128, 512 blocks -> 2/CU.
__global__ __launch_bounds__(256) void gemm_out(const f16* __restrict__ A,
                                                const f16* __restrict__ B,
                                                const float* __restrict__ bias,
                                                float* __restrict__ Cout) {
    __shared__ __align__(16) f16 As[64 * 64];    // 8KB
    __shared__ __align__(16) f16 Bs[128 * 64];   // 16KB
    const int tid  = threadIdx.x;
    const int lane = tid & 63, wave = tid >> 6;
    const int lm = lane & 15, quad = lane >> 4;
    const int wm = wave >> 1, wn = wave & 1;

    const int bid = blockIdx.x;                     // 1D grid, 512 blocks
    const int wid = (bid & 7) * 64 + (bid >> 3);    // bijective XCD chunking
    const int bx = wid & 15, by = wid >> 4;
    const int tn0 = bx * 128, tm0 = by * 64;

    const f16* Aga[2];
    const f16* Bga[4];
    f16* Ald[2];
    f16* Bld[4];
#pragma unroll
    for (int i = 0; i < 2; i++) {
        int c = i * 256 + tid;
        int row = c >> 3, ch = c & 7;
        int srcoff = row * E_ + ((ch ^ (row & 7)) * 8);
        Aga[i] = A + (size_t)tm0 * E_ + srcoff;
        Ald[i] = &As[c * 8];
    }
#pragma unroll
    for (int i = 0; i < 4; i++) {
        int c = i * 256 + tid;
        int row = c >> 3, ch = c & 7;
        int srcoff = row * E_ + ((ch ^ (row & 7)) * 8);
        Bga[i] = B + (size_t)tn0 * E_ + srcoff;
        Bld[i] = &Bs[c * 8];
    }

    const f32x4 vzero = {0.f, 0.f, 0.f, 0.f};
    f32x4 acc[2][4];
#pragma unroll
    for (int i = 0; i < 2; i++)
#pragma unroll
        for (int j = 0; j < 4; j++) acc[i][j] = vzero;

    const int e7 = lm & 7;
    for (int k0 = 0; k0 < E_; k0 += 64) {
        __syncthreads();
#pragma unroll
        for (int i = 0; i < 2; i++) GLDS(Aga[i] + k0, Ald[i]);
#pragma unroll
        for (int i = 0; i < 4; i++) GLDS(Bga[i] + k0, Bld[i]);
        __syncthreads();
#pragma unroll
        for (int kk = 0; kk < 2; kk++) {
            f16x8 af[2], bfr[4];
#pragma unroll
            for (int i = 0; i < 2; i++)
                af[i] = *(const f16x8*)&As[(wm * 32 + i * 16 + lm) * 64 +
                                           (((kk * 4 + quad) ^ e7) * 8)];
#pragma unroll
            for (int j = 0; j < 4; j++)
                bfr[j] = *(const f16x8*)&Bs[(wn * 64 + j * 16 + lm) * 64 +
                                            (((kk * 4 + quad) ^ e7) * 8)];
#pragma unroll
            for (int i = 0; i < 2; i++)
#pragma unroll
                for (int j = 0; j < 4; j++)
                    acc[i][j] = __builtin_amdgcn_mfma_f32_16x16x32_f16(af[i], bfr[j],
                                                                       acc[i][j], 0, 0, 0);
        }
    }

#pragma unroll
    for (int i = 0; i < 2; i++) {
#pragma unroll
        for (int j = 0; j < 4; j++) {
            const int n = tn0 + wn * 64 + j * 16 + lm;
            const float bv = bias[n];
#pragma unroll
            for (int r = 0; r < 4; r++) {
                const int m = tm0 + wm * 32 + i * 16 + quad * 4 + r;
                Cout[(size_t)m * E_ + n] = acc[i][j][r] + bv;
            }
        }
    }
}

// ---------------------------------------------------------------- launch
extern "C" void kernel_launch(void* const* d_in, const int* in_sizes, int n_in,
                              void* d_out, int out_size, void* d_ws, size_t ws_size,
                              hipStream_t stream) {
    const float* x     = (const float*)d_in[0];
    const float* w_qkv = (const float*)d_in[1];
    const float* b_qkv = (const float*)d_in[2];
    const float* w_out = (const float*)d_in[3];
    const float* b_out = (const float*)d_in[4];
    float* out = (float*)d_out;

    char* ws = (char*)d_ws;
    f16* xb  = (f16*)ws; ws += (size_t)S_ * E_ * 2;
    f16* wqb = (f16*)ws; ws += (size_t)3 * E_ * E_ * 2;
    f16* wob = (f16*)ws; ws += (size_t)E_ * E_ * 2;
    f16* Qm  = (f16*)ws; ws += (size_t)H_ * S_ * D_ * 2;
    f16* Km  = (f16*)ws; ws += (size_t)H_ * S_ * D_ * 2;
    f16* VTm = (f16*)ws; ws += (size_t)H_ * D_ * S_ * 2;
    f16* Om  = (f16*)ws; ws += (size_t)S_ * E_ * 2;

    // attn partials reuse the xb+wqb region (32MB, dead after gemm_qkv):
    // Opart 816 units x 128 rows x 128 d (f16) = 25.5MB; Mlp at +27MB.
    f16*    Opart = (f16*)d_ws;
    float2* Mlp   = (float2*)((char*)d_ws + (27u << 20));

    cvt_all<<<20480, 256, 0, stream>>>(x, w_qkv, w_out, xb, wqb, wob);
    gemm_qkv<<<768, 256, 0, stream>>>(xb, wqb, b_qkv, Qm, Km, VTm);
    attn_part<<<816, 256, 0, stream>>>(Qm, Km, VTm, Om, Opart, Mlp);
    attn_merge<<<3328, 256, 0, stream>>>(Opart, Mlp, Om);
    gemm_out<<<512, 256, 0, stream>>>(Om, wob, b_out, out);
}

// Round 9
// 261.409 us; speedup vs baseline: 1.5321x; 1.0102x over previous
//
#include <hip/hip_runtime.h>
#include <math.h>

#define S_ 2048
#define E_ 2048
#define H_ 16
#define D_ 128

typedef _Float16 f16;
typedef _Float16 f16x8 __attribute__((ext_vector_type(8)));
typedef _Float16 f16x4 __attribute__((ext_vector_type(4)));
typedef float f32x4 __attribute__((ext_vector_type(4)));

// async global->LDS, 16B per lane. LDS dest must be wave-uniform base + lane*16.
#define GLDS(g, l)                                                            \
    __builtin_amdgcn_global_load_lds(                                         \
        (const __attribute__((address_space(1))) void*)(g),                   \
        (__attribute__((address_space(3))) void*)(l), 16, 0, 0)

// ---------------------------------------------------------------- convert (fused: x, w_qkv, w_out)
__global__ __launch_bounds__(256) void cvt_all(const float* __restrict__ x,
                                               const float* __restrict__ wq,
                                               const float* __restrict__ wo,
                                               f16* __restrict__ xb,
                                               f16* __restrict__ wqb,
                                               f16* __restrict__ wob) {
    const int b = blockIdx.x;
    const float* in;
    f16* out;
    int lb;
    if (b < 4096)       { in = x;  out = xb;  lb = b; }
    else if (b < 16384) { in = wq; out = wqb; lb = b - 4096; }
    else                { in = wo; out = wob; lb = b - 16384; }
    const int i = (lb * 256 + threadIdx.x) * 4;
    float4 v = *(const float4*)(in + i);
    f16x4 o;
    o[0] = (f16)v.x; o[1] = (f16)v.y; o[2] = (f16)v.z; o[3] = (f16)v.w;
    *(f16x4*)(out + i) = o;
}

// ---------------------------------------------------------------- QKV GEMM
// BK=64, conflict-free swizzled LDS via pre-swizzled GLDS source (R8-verified:
// bank conflicts = 0). Grid: PLAIN row-major 2D (R8 lesson: since 48 = 0 mod 8,
// bx = bid mod 8 per XCD -> each XCD holds only 6 B-panels (3MB, L2-resident)
// and streams A; the explicit "XCD chunking" gave each XCD ALL of B -> 24MB
// L2 thrash, FETCH 45->150MB).
__global__ __launch_bounds__(256, 3) void gemm_qkv(const f16* __restrict__ A,
                                                   const f16* __restrict__ B,
                                                   const float* __restrict__ bias,
                                                   f16* __restrict__ Qm,
                                                   f16* __restrict__ Km,
                                                   f16* __restrict__ VTm) {
    __shared__ __align__(16) f16 As[128 * 64];   // [row][chunk-swizzled], 16KB
    __shared__ __align__(16) f16 Bs[128 * 64];
    const int tid  = threadIdx.x;
    const int lane = tid & 63, wave = tid >> 6;
    const int lm = lane & 15, quad = lane >> 4;
    const int wm = wave >> 1, wn = wave & 1;
    const int tn0 = blockIdx.x * 128;
    const int tm0 = blockIdx.y * 128;

    // staging: 4 chunks of 16B per thread per matrix; LDS linear, src inverse-swizzled
    const f16* Aga[4];
    const f16* Bga[4];
    f16* Ald[4];
    f16* Bld[4];
#pragma unroll
    for (int i = 0; i < 4; i++) {
        int c = i * 256 + tid;
        int row = c >> 3, ch = c & 7;
        int srcoff = row * E_ + ((ch ^ (row & 7)) * 8);
        Aga[i] = A + (size_t)tm0 * E_ + srcoff;
        Bga[i] = B + (size_t)tn0 * E_ + srcoff;
        Ald[i] = &As[c * 8];
        Bld[i] = &Bs[c * 8];
    }

    const f32x4 vzero = {0.f, 0.f, 0.f, 0.f};
    f32x4 acc[4][4];
#pragma unroll
    for (int i = 0; i < 4; i++)
#pragma unroll
        for (int j = 0; j < 4; j++) acc[i][j] = vzero;

    const int e7 = lm & 7;
    for (int k0 = 0; k0 < E_; k0 += 64) {
        __syncthreads();
#pragma unroll
        for (int i = 0; i < 4; i++) {
            GLDS(Aga[i] + k0, Ald[i]);
            GLDS(Bga[i] + k0, Bld[i]);
        }
        __syncthreads();
#pragma unroll
        for (int kk = 0; kk < 2; kk++) {
            f16x8 af[4], bfr[4];
#pragma unroll
            for (int i = 0; i < 4; i++)
                af[i] = *(const f16x8*)&As[(wm * 64 + i * 16 + lm) * 64 +
                                           (((kk * 4 + quad) ^ e7) * 8)];
#pragma unroll
            for (int j = 0; j < 4; j++)
                bfr[j] = *(const f16x8*)&Bs[(wn * 64 + j * 16 + lm) * 64 +
                                            (((kk * 4 + quad) ^ e7) * 8)];
#pragma unroll
            for (int i = 0; i < 4; i++)
#pragma unroll
                for (int j = 0; j < 4; j++)
                    acc[i][j] = __builtin_amdgcn_mfma_f32_16x16x32_f16(af[i], bfr[j],
                                                                       acc[i][j], 0, 0, 0);
        }
    }

    const float qscale = 0.08838834764831845f;  // 1/sqrt(128), prefolded into Q
#pragma unroll
    for (int i = 0; i < 4; i++) {
#pragma unroll
        for (int j = 0; j < 4; j++) {
            const int n = tn0 + wn * 64 + j * 16 + lm;
            const int which = n >> 11;
            const int h = (n >> 7) & 15;
            const int d = n & 127;
            const float bv = bias[n];
#pragma unroll
            for (int r = 0; r < 4; r++) {
                const int m = tm0 + wm * 64 + i * 16 + quad * 4 + r;
                float fv = acc[i][j][r] + bv;
                if (which == 0)      Qm[((size_t)h * S_ + m) * D_ + d] = (f16)(fv * qscale);
                else if (which == 1) Km[((size_t)h * S_ + m) * D_ + d] = (f16)fv;
                else                 VTm[((size_t)h * D_ + d) * S_ + m] = (f16)fv;
            }
        }
    }
}

// ---------------------------------------------------------------- attention (partial)
// R7 structure (verified): GLDS pre-swizzled staging, K/V double-buffered with
// ONE barrier/iter, Ps 2KB/wave, defer-max, 2 q-row-tiles/wave, flash-decode
// segments of 6 kv-tiles -> 816 uniform blocks; LDS 72KB -> 2 blocks/CU.
__global__ __launch_bounds__(256, 2) void attn_part(const f16* __restrict__ Qm,
                                                    const f16* __restrict__ Km,
                                                    const f16* __restrict__ VTm,
                                                    f16* __restrict__ Om,
                                                    f16* __restrict__ Opart,
                                                    float2* __restrict__ Mlp) {
    __shared__ __align__(16) f16 Ks[2][64 * 128];   // [buf][key][d-chunk swizzled]
    __shared__ __align__(16) f16 VTs[2][128 * 64];  // [buf][d][key-chunk swizzled]
    __shared__ __align__(16) f16 Ps[4][1024];       // per-wave 2KB, reused P0/P1

    const int tid  = threadIdx.x;
    const int lane = tid & 63, wave = tid >> 6;
    const int lm = lane & 15, quad = lane >> 4;
    const int bx = blockIdx.x;
    const int h  = bx & 15;
    const int u  = 50 - (bx >> 4);   // canonical unit index, heavy-first dispatch

    // unit -> (128-row q-tile qt, kv-segment of 6 tiles). tiles(qt) = 2qt+2.
    int qt, seg;
    if (u < 3)       { qt = u;                 seg = 0; }
    else if (u < 9)  { qt = 3  + (u - 3) / 2;  seg = (u - 3) % 2; }
    else if (u < 18) { qt = 6  + (u - 9) / 3;  seg = (u - 9) % 3; }
    else if (u < 30) { qt = 9  + (u - 18) / 4; seg = (u - 18) % 4; }
    else if (u < 45) { qt = 12 + (u - 30) / 5; seg = (u - 30) % 5; }
    else             { qt = 15;                seg = u - 45; }
    const int t0 = seg * 6;
    const int ntiles = 2 * qt + 2;
    const int t1 = (t0 + 6 < ntiles) ? (t0 + 6) : ntiles;

    const f16* KmH  = Km  + (size_t)h * S_ * D_;
    const f16* VTmH = VTm + (size_t)h * D_ * S_;
    const f16* QmH  = Qm  + (size_t)h * S_ * D_;

    // GLDS staging offsets: linear LDS slot c -> inverse-swizzled global chunk.
    int kgo[4], vgo[4];
#pragma unroll
    for (int i = 0; i < 4; i++) {
        int c = (wave * 4 + i) * 64 + lane;          // 16B-chunk linear index
        int key = c >> 4, dcS = c & 15;
        int dc = (dcS & 8) | ((dcS & 7) ^ (key & 7));
        kgo[i] = key * 128 + dc * 8;
        int d = c >> 3, scS = c & 7;
        int sc = scS ^ (d & 7);
        vgo[i] = d * 2048 + sc * 8;
    }

#define STAGE(B, T)                                                           \
    {                                                                         \
        const f16* kt_ = KmH + (size_t)(T) * 8192;                            \
        const f16* vt_ = VTmH + (T) * 64;                                     \
        _Pragma("unroll")                                                     \
        for (int i = 0; i < 4; i++) {                                         \
            GLDS(kt_ + kgo[i], &Ks[B][(wave * 4 + i) * 512]);                 \
            GLDS(vt_ + vgo[i], &VTs[B][(wave * 4 + i) * 512]);                \
        }                                                                     \
    }

    const f32x4 vzero = {0.f, 0.f, 0.f, 0.f};
    f32x4 o0[8], o1[8];
#pragma unroll
    for (int f = 0; f < 8; f++) { o0[f] = vzero; o1[f] = vzero; }
    float mi0 = -INFINITY, li0 = 0.f;
    float mi1 = -INFINITY, li1 = 0.f;

    const int q0c = qt * 128 + wave * 32;          // wave's 32-row chunk
    const int qr0 = q0c + lm;                      // n=0 row
    const int qr1 = q0c + 16 + lm;                 // n=1 row
    f16x8 qf0[4], qf1[4];
#pragma unroll
    for (int kc = 0; kc < 4; kc++) {
        qf0[kc] = *(const f16x8*)(QmH + (size_t)qr0 * D_ + kc * 32 + quad * 8);
        qf1[kc] = *(const f16x8*)(QmH + (size_t)qr1 * D_ + kc * 32 + quad * 8);
    }

    char* psb = (char*)&Ps[wave][0];
    const int swz = (lm & 7) << 4;

    // prologue: stage first tile into buffer 0
    STAGE(0, t0);
    __syncthreads();

    for (int t = t0; t < t1; t++) {
        const int cur = (t - t0) & 1;
        const int k0 = t * 64;

        if (t + 1 < t1) STAGE(cur ^ 1, t + 1);   // async into other buffer

        // ---- S^T = K * Q^T : each kf read feeds BOTH n-tiles
        f32x4 sfr0[4], sfr1[4];
        __builtin_amdgcn_s_setprio(1);
#pragma unroll
        for (int j = 0; j < 4; j++) {
            f32x4 a0 = vzero, a1 = vzero;
#pragma unroll
            for (int kc = 0; kc < 4; kc++) {
                int dc = kc * 4 + quad;
                int sc = (dc & 8) | ((dc & 7) ^ (lm & 7));
                f16x8 kf = *(const f16x8*)&Ks[cur][(j * 16 + lm) * 128 + sc * 8];
                a0 = __builtin_amdgcn_mfma_f32_16x16x32_f16(kf, qf0[kc], a0, 0, 0, 0);
                a1 = __builtin_amdgcn_mfma_f32_16x16x32_f16(kf, qf1[kc], a1, 0, 0, 0);
            }
            sfr0[j] = a0; sfr1[j] = a1;
        }
        __builtin_amdgcn_s_setprio(0);

        // ---- online softmax, two independent 16-row chains (n=0, n=1)
        const bool mayMask = (k0 + 63 > q0c);
        float vmax0 = -3e38f, vmax1 = -3e38f;
#pragma unroll
        for (int j = 0; j < 4; j++)
#pragma unroll
            for (int r = 0; r < 4; r++) {
                float x0 = sfr0[j][r], x1 = sfr1[j][r];
                if (mayMask) {
                    int key = k0 + j * 16 + quad * 4 + r;
                    if (key > qr0) x0 = -1e30f;
                    if (key > qr1) x1 = -1e30f;
                }
                sfr0[j][r] = x0; sfr1[j][r] = x1;
                vmax0 = fmaxf(vmax0, x0);
                vmax1 = fmaxf(vmax1, x1);
            }
        vmax0 = fmaxf(vmax0, __shfl_xor(vmax0, 16));
        vmax0 = fmaxf(vmax0, __shfl_xor(vmax0, 32));
        vmax1 = fmaxf(vmax1, __shfl_xor(vmax1, 16));
        vmax1 = fmaxf(vmax1, __shfl_xor(vmax1, 32));
        // defer-max (T13): rescale only when a row's max grew by > 8
        if (!__all(fmaxf(vmax0 - mi0, vmax1 - mi1) <= 8.0f)) {
            const float mn0 = fmaxf(mi0, vmax0);
            const float mn1 = fmaxf(mi1, vmax1);
            const float al0 = __expf(mi0 - mn0);
            const float al1 = __expf(mi1 - mn1);
            li0 *= al0; li1 *= al1;
#pragma unroll
            for (int f = 0; f < 8; f++) {
                o0[f][0] *= al0; o0[f][1] *= al0; o0[f][2] *= al0; o0[f][3] *= al0;
                o1[f][0] *= al1; o1[f][1] *= al1; o1[f][2] *= al1; o1[f][3] *= al1;
            }
            mi0 = mn0; mi1 = mn1;
        }
        // P (bounded by e^8, f16-safe): n=0 through the 2KB Ps, then n=1
        float rs0 = 0.f, rs1 = 0.f;
#pragma unroll
        for (int j = 0; j < 4; j++) {
            f16x4 pk0;
#pragma unroll
            for (int r = 0; r < 4; r++) {
                float p0 = __expf(sfr0[j][r] - mi0);
                rs0 += p0;
                pk0[r] = (f16)p0;
            }
            *(f16x4*)(psb + lm * 128 + ((j * 32 + quad * 8) ^ swz)) = pk0;
        }
        f16x8 pb0[2];
#pragma unroll
        for (int kc = 0; kc < 2; kc++)
            pb0[kc] = *(const f16x8*)(psb + lm * 128 + ((kc * 64 + quad * 16) ^ swz));
#pragma unroll
        for (int j = 0; j < 4; j++) {
            f16x4 pk1;
#pragma unroll
            for (int r = 0; r < 4; r++) {
                float p1 = __expf(sfr1[j][r] - mi1);
                rs1 += p1;
                pk1[r] = (f16)p1;
            }
            *(f16x4*)(psb + lm * 128 + ((j * 32 + quad * 8) ^ swz)) = pk1;
        }
        f16x8 pb1[2];
#pragma unroll
        for (int kc = 0; kc < 2; kc++)
            pb1[kc] = *(const f16x8*)(psb + lm * 128 + ((kc * 64 + quad * 16) ^ swz));
        rs0 += __shfl_xor(rs0, 16);
        rs0 += __shfl_xor(rs0, 32);
        rs1 += __shfl_xor(rs1, 16);
        rs1 += __shfl_xor(rs1, 32);
        li0 += rs0;
        li1 += rs1;

        // ---- O^T += V^T * P^T : each vf read feeds BOTH n-tiles
        __builtin_amdgcn_s_setprio(1);
#pragma unroll
        for (int f = 0; f < 8; f++) {
#pragma unroll
            for (int kc = 0; kc < 2; kc++) {
                int sc = (kc * 4 + quad) ^ (lm & 7);
                f16x8 vf = *(const f16x8*)&VTs[cur][(f * 16 + lm) * 64 + sc * 8];
                o0[f] = __builtin_amdgcn_mfma_f32_16x16x32_f16(vf, pb0[kc], o0[f], 0, 0, 0);
                o1[f] = __builtin_amdgcn_mfma_f32_16x16x32_f16(vf, pb1[kc], o1[f], 0, 0, 0);
            }
        }
        __builtin_amdgcn_s_setprio(0);

        __syncthreads();   // own GLDS drained (hidden by compute); all waves done
    }

    const float inv0 = 1.f / li0;
    const float inv1 = 1.f / li1;
    if (qt < 3) {
        // single segment: normalized output directly
#pragma unroll
        for (int f = 0; f < 8; f++) {
            f16x4 ov0, ov1;
#pragma unroll
            for (int r = 0; r < 4; r++) {
                ov0[r] = (f16)(o0[f][r] * inv0);
                ov1[r] = (f16)(o1[f][r] * inv1);
            }
            *(f16x4*)(Om + (size_t)qr0 * E_ + h * 128 + f * 16 + quad * 4) = ov0;
            *(f16x4*)(Om + (size_t)qr1 * E_ + h * 128 + f * 16 + quad * 4) = ov1;
        }
    } else {
        // partial: NORMALIZED O (f16) + per-row (m, l)
        const int unit = h * 51 + u;
        f16* op0 = Opart + (size_t)unit * 16384 + (wave * 32 + lm) * 128;
        f16* op1 = op0 + 16 * 128;
#pragma unroll
        for (int f = 0; f < 8; f++) {
            f16x4 ov0, ov1;
#pragma unroll
            for (int r = 0; r < 4; r++) {
                ov0[r] = (f16)(o0[f][r] * inv0);
                ov1[r] = (f16)(o1[f][r] * inv1);
            }
            *(f16x4*)(op0 + f * 16 + quad * 4) = ov0;
            *(f16x4*)(op1 + f * 16 + quad * 4) = ov1;
        }
        if (quad == 0) {
            Mlp[unit * 128 + wave * 32 + lm]      = make_float2(mi0, li0);
            Mlp[unit * 128 + wave * 32 + 16 + lm] = make_float2(mi1, li1);
        }
    }
#undef STAGE
}

// ---------------------------------------------------------------- attention merge
__global__ __launch_bounds__(256) void attn_merge(const f16* __restrict__ Opart,
                                                  const float2* __restrict__ Mlp,
                                                  f16* __restrict__ Om) {
    const int idx = blockIdx.x * 256 + threadIdx.x;   // 851968 total
    const int d4  = idx & 31;
    const int h   = (idx >> 5) & 15;
    const int r5  = idx >> 9;            // 0..1663
    const int row = 384 + r5;
    const int qt  = row >> 7;            // 3..15 (128-row tiles)
    const int rw  = row & 127;
    int ub, nseg;
    if (qt < 6)       { ub = 3  + (qt - 3) * 2;  nseg = 2; }
    else if (qt < 9)  { ub = 9  + (qt - 6) * 3;  nseg = 3; }
    else if (qt < 12) { ub = 18 + (qt - 9) * 4;  nseg = 4; }
    else if (qt < 15) { ub = 30 + (qt - 12) * 5; nseg = 5; }
    else              { ub = 45;                 nseg = 6; }
    const int base_unit = h * 51 + ub;

    float m = -INFINITY;
    for (int s = 0; s < nseg; s++)
        m = fmaxf(m, Mlp[(base_unit + s) * 128 + rw].x);

    float L = 0.f;
    float a0 = 0.f, a1 = 0.f, a2 = 0.f, a3 = 0.f;
    for (int s = 0; s < nseg; s++) {
        float2 ml = Mlp[(base_unit + s) * 128 + rw];
        float wl = __expf(ml.x - m) * ml.y;
        L += wl;
        f16x4 ov = *(const f16x4*)(Opart + (size_t)(base_unit + s) * 16384 + rw * 128 + d4 * 4);
        a0 += wl * (float)ov[0];
        a1 += wl * (float)ov[1];
        a2 += wl * (float)ov[2];
        a3 += wl * (float)ov[3];
    }
    const float inv = 1.f / L;
    f16x4 res;
    res[0] = (f16)(a0 * inv); res[1] = (f16)(a1 * inv);
    res[2] = (f16)(a2 * inv); res[3] = (f16)(a3 * inv);
    *(f16x4*)(Om + (size_t)row * E_ + h * 128 + d4 * 4) = res;
}

// ---------------------------------------------------------------- out GEMM
// BK=64, conflict-free swizzle (R8-verified). Plain 2D grid: 16 = 0 mod 8 ->
// bx = bid mod 8 per XCD -> 2 B-panels/XCD (1MB, L2-resident), A streams.
__global__ __launch_bounds__(256) void gemm_out(const f16* __restrict__ A,
                                                const f16* __restrict__ B,
                                                const float* __restrict__ bias,
                                                float* __restrict__ Cout) {
    __shared__ __align__(16) f16 As[64 * 64];    // 8KB
    __shared__ __align__(16) f16 Bs[128 * 64];   // 16KB
    const int tid  = threadIdx.x;
    const int lane = tid & 63, wave = tid >> 6;
    const int lm = lane & 15, quad = lane >> 4;
    const int wm = wave >> 1, wn = wave & 1;
    const int tn0 = blockIdx.x * 128;
    const int tm0 = blockIdx.y * 64;

    const f16* Aga[2];
    const f16* Bga[4];
    f16* Ald[2];
    f16* Bld[4];
#pragma unroll
    for (int i = 0; i < 2; i++) {
        int c = i * 256 + tid;
        int row = c >> 3, ch = c & 7;
        int srcoff = row * E_ + ((ch ^ (row & 7)) * 8);
        Aga[i] = A + (size_t)tm0 * E_ + srcoff;
        Ald[i] = &As[c * 8];
    }
#pragma unroll
    for (int i = 0; i < 4; i++) {
        int c = i * 256 + tid;
        int row = c >> 3, ch = c & 7;
        int srcoff = row * E_ + ((ch ^ (row & 7)) * 8);
        Bga[i] = B + (size_t)tn0 * E_ + srcoff;
        Bld[i] = &Bs[c * 8];
    }

    const f32x4 vzero = {0.f, 0.f, 0.f, 0.f};
    f32x4 acc[2][4];
#pragma unroll
    for (int i = 0; i < 2; i++)
#pragma unroll
        for (int j = 0; j < 4; j++) acc[i][j] = vzero;

    const int e7 = lm & 7;
    for (int k0 = 0; k0 < E_; k0 += 64) {
        __syncthreads();
#pragma unroll
        for (int i = 0; i < 2; i++) GLDS(Aga[i] + k0, Ald[i]);
#pragma unroll
        for (int i = 0; i < 4; i++) GLDS(Bga[i] + k0, Bld[i]);
        __syncthreads();
#pragma unroll
        for (int kk = 0; kk < 2; kk++) {
            f16x8 af[2], bfr[4];
#pragma unroll
            for (int i = 0; i < 2; i++)
                af[i] = *(const f16x8*)&As[(wm * 32 + i * 16 + lm) * 64 +
                                           (((kk * 4 + quad) ^ e7) * 8)];
#pragma unroll
            for (int j = 0; j < 4; j++)
                bfr[j] = *(const f16x8*)&Bs[(wn * 64 + j * 16 + lm) * 64 +
                                            (((kk * 4 + quad) ^ e7) * 8)];
#pragma unroll
            for (int i = 0; i < 2; i++)
#pragma unroll
                for (int j = 0; j < 4; j++)
                    acc[i][j] = __builtin_amdgcn_mfma_f32_16x16x32_f16(af[i], bfr[j],
                                                                       acc[i][j], 0, 0, 0);
        }
    }

#pragma unroll
    for (int i = 0; i < 2; i++) {
#pragma unroll
        for (int j = 0; j < 4; j++) {
            const int n = tn0 + wn * 64 + j * 16 + lm;
            const float bv = bias[n];
#pragma unroll
            for (int r = 0; r < 4; r++) {
                const int m = tm0 + wm * 32 + i * 16 + quad * 4 + r;
                Cout[(size_t)m * E_ + n] = acc[i][j][r] + bv;
            }
        }
    }
}

// ---------------------------------------------------------------- launch
extern "C" void kernel_launch(void* const* d_in, const int* in_sizes, int n_in,
                              void* d_out, int out_size, void* d_ws, size_t ws_size,
                              hipStream_t stream) {
    const float* x     = (const float*)d_in[0];
    const float* w_qkv = (const float*)d_in[1];
    const float* b_qkv = (const float*)d_in[2];
    const float* w_out = (const float*)d_in[3];
    const float* b_out = (const float*)d_in[4];
    float* out = (float*)d_out;

    char* ws = (char*)d_ws;
    f16* xb  = (f16*)ws; ws += (size_t)S_ * E_ * 2;
    f16* wqb = (f16*)ws; ws += (size_t)3 * E_ * E_ * 2;
    f16* wob = (f16*)ws; ws += (size_t)E_ * E_ * 2;
    f16* Qm  = (f16*)ws; ws += (size_t)H_ * S_ * D_ * 2;
    f16* Km  = (f16*)ws; ws += (size_t)H_ * S_ * D_ * 2;
    f16* VTm = (f16*)ws; ws += (size_t)H_ * D_ * S_ * 2;
    f16* Om  = (f16*)ws; ws += (size_t)S_ * E_ * 2;

    // attn partials reuse the xb+wqb region (32MB, dead after gemm_qkv):
    // Opart 816 units x 128 rows x 128 d (f16) = 25.5MB; Mlp at +27MB.
    f16*    Opart = (f16*)d_ws;
    float2* Mlp   = (float2*)((char*)d_ws + (27u << 20));

    cvt_all<<<20480, 256, 0, stream>>>(x, w_qkv, w_out, xb, wqb, wob);
    gemm_qkv<<<dim3(48, 16), 256, 0, stream>>>(xb, wqb, b_qkv, Qm, Km, VTm);
    attn_part<<<816, 256, 0, stream>>>(Qm, Km, VTm, Om, Opart, Mlp);
    attn_merge<<<3328, 256, 0, stream>>>(Opart, Mlp, Om);
    gemm_out<<<dim3(16, 32), 256, 0, stream>>>(Om, wob, b_out, out);
}